// Round 1
// baseline (2447.266 us; speedup 1.0000x reference)
//
#include <hip/hip_runtime.h>

#define HW2 320
#define NB 8
#define NC 16
#define NPIX (HW2*HW2)        // 102400
#define NVEC (NB*NPIX)        // 819200
#define CGI 10
#define FSCALE (1.0f/102400.0f)  // ortho fwd (1/320) * ortho inv (1/320)

// ---------- complex helpers ----------
__device__ inline float2 cadd(float2 a, float2 b){return make_float2(a.x+b.x, a.y+b.y);}
__device__ inline float2 csub(float2 a, float2 b){return make_float2(a.x-b.x, a.y-b.y);}
__device__ inline float2 cmul(float2 a, float2 b){return make_float2(a.x*b.x-a.y*b.y, a.x*b.y+a.y*b.x);}
__device__ inline float2 cmulc(float2 a, float2 b){return make_float2(a.x*b.x+a.y*b.y, a.y*b.x-a.x*b.y);} // a*conj(b)
__device__ inline float2 cscale(float2 a, float s){return make_float2(a.x*s, a.y*s);}
__device__ inline int rev6(int t){ return (int)(__brev((unsigned)t) >> 26); }
__device__ inline float2 shflx2(float2 a, int m){ return make_float2(__shfl_xor(a.x,m,64), __shfl_xor(a.y,m,64)); }
__device__ inline float2 shfl2(float2 a, int l){ return make_float2(__shfl(a.x,l,64), __shfl(a.y,l,64)); }

// twiddle table accessor: re/im planes with stride (LDS resident)
struct TwTab { const float* re; const float* im; int str; };
__device__ inline float2 twld(const TwTab tw, int i){ return make_float2(tw.re[i*tw.str], tw.im[i*tw.str]); }

// ---------- radix-5 (in registers). DIR=-1 fwd, +1 inv. Unnormalized. ----------
template<int DIR>
__device__ inline void radix5(float2 v[5]) {
  const float c1 = 0.30901699437494745f, s1 = 0.9510565162951535f;
  const float c2 = -0.8090169943749473f, s2 = 0.5877852522924731f;
  float2 t1 = cadd(v[1], v[4]), t2 = csub(v[1], v[4]);
  float2 t3 = cadd(v[2], v[3]), t4 = csub(v[2], v[3]);
  float2 y0 = cadd(v[0], cadd(t1, t3));
  float2 a1 = make_float2(v[0].x + c1*t1.x + c2*t3.x, v[0].y + c1*t1.y + c2*t3.y);
  float2 a2 = make_float2(v[0].x + c2*t1.x + c1*t3.x, v[0].y + c2*t1.y + c1*t3.y);
  float2 b1 = make_float2(s1*t2.x + s2*t4.x, s1*t2.y + s2*t4.y);
  float2 b2 = make_float2(s2*t2.x - s1*t4.x, s2*t2.y - s1*t4.y);
  const float sg = (float)DIR;
  float2 ib1 = make_float2(-sg*b1.y, sg*b1.x);
  float2 ib2 = make_float2(-sg*b2.y, sg*b2.x);
  v[0] = y0;
  v[1] = cadd(a1, ib1); v[4] = csub(a1, ib1);
  v[2] = cadd(a2, ib2); v[3] = csub(a2, ib2);
}

// ---------- 320-pt FFT across one wave. ----------
// fwd: input  v[j] = x[t+64j]  ->  output v[q] = X[5*rev6(t)+q]
__device__ inline void fft320_fwd(float2 v[5], int t, const TwTab tw) {
  radix5<-1>(v);
  #pragma unroll
  for (int q = 1; q < 5; ++q) v[q] = cmul(v[q], twld(tw, q*t));
  #pragma unroll
  for (int h = 32; h >= 1; h >>= 1) {
    const bool up = (t & h) != 0;
    float2 w = twld(tw, 5*(t & (h-1))*(32/h));  // w64^{(t mod h)*(32/h)} = w320[5*...]
    #pragma unroll
    for (int q = 0; q < 5; ++q) {
      float2 o = shflx2(v[q], h);
      v[q] = up ? cmul(csub(o, v[q]), w) : cadd(v[q], o);
    }
  }
}
// inv (unnormalized IDFT sum): input v[q] = Y[5*rev6(t)+q] -> output v[j] = z[t+64j]
__device__ inline void fft320_inv(float2 v[5], int t, const TwTab tw) {
  #pragma unroll
  for (int h = 1; h <= 32; h <<= 1) {
    const bool up = (t & h) != 0;
    float2 w = twld(tw, 5*(t & (h-1))*(32/h));
    float2 wc = make_float2(w.x, -w.y);
    #pragma unroll
    for (int q = 0; q < 5; ++q) {
      float2 mine = up ? cmul(v[q], wc) : v[q];
      float2 o = shflx2(mine, h);
      v[q] = up ? csub(o, mine) : cadd(mine, o);
    }
  }
  #pragma unroll
  for (int q = 1; q < 5; ++q) v[q] = cmulc(v[q], twld(tw, q*t));
  radix5<1>(v);
}

// ---------- twiddle table init (double precision trig) ----------
__global__ void k_twiddle(float2* tw) {
  int m = blockIdx.x*blockDim.x + threadIdx.x;
  if (m < 320) {
    double a = -2.0 * 3.14159265358979323846 * (double)m / 320.0;
    tw[m] = make_float2((float)cos(a), (float)sin(a));
  }
}

// ---------- r = us + mu*rec ; p = r ; b = 0  (planar -> interleaved) ----------
__global__ void k_init(const float* __restrict__ us, const float* __restrict__ rec,
                       const float* __restrict__ mu,
                       float2* r, float2* p, float2* bv) {
  int i = blockIdx.x*blockDim.x + threadIdx.x;
  if (i >= NVEC) return;
  float m = mu[0];
  int b = i / NPIX, hw = i % NPIX;
  float re = us[(size_t)(b*2+0)*NPIX + hw] + m * rec[(size_t)(b*2+0)*NPIX + hw];
  float im = us[(size_t)(b*2+1)*NPIX + hw] + m * rec[(size_t)(b*2+1)*NPIX + hw];
  float2 v = make_float2(re, im);
  r[i] = v; p[i] = v; bv[i] = make_float2(0.f, 0.f);
}

// ---------- A: coil-project (p*csm*S) + forward row FFT -> K ----------
__global__ __launch_bounds__(256) void k_proj_rowfft(
    const float2* __restrict__ pv, const float* __restrict__ csr,
    const float* __restrict__ csi, float2* __restrict__ K,
    const float2* __restrict__ twg, int b0) {
  __shared__ float twre[320], twim[320];
  __shared__ float2 stage[4][320];
  for (int i = threadIdx.x; i < 320; i += 256) { float2 w = twg[i]; twre[i]=w.x; twim[i]=w.y; }
  __syncthreads();
  const TwTab tw{twre, twim, 1};
  int wid = blockIdx.x*4 + (threadIdx.x >> 6);
  int t = threadIdx.x & 63;
  int row = wid % HW2;
  int c   = (wid / HW2) % NC;
  int bl  = wid / (HW2*NC);
  int b   = b0 + bl;
  const float2* prow = pv + ((size_t)(b*HW2) + row)*HW2;
  size_t cs = ((size_t)((b*NC + c)*HW2) + row)*HW2;
  float sgn = ((row + t) & 1) ? -1.f : 1.f;   // (-1)^{row+n}, n=t+64j
  float2 v[5];
  #pragma unroll
  for (int j = 0; j < 5; ++j) {
    int n = t + 64*j;
    float2 cv = make_float2(csr[cs+n], csi[cs+n]);
    v[j] = cscale(cmul(prow[n], cv), sgn);
  }
  fft320_fwd(v, t, tw);
  int w = threadIdx.x >> 6, rt = rev6(t);
  #pragma unroll
  for (int q = 0; q < 5; ++q) stage[w][5*rt + q] = v[q];   // wave-local
  float2* Krow = K + ((size_t)((bl*NC + c)*HW2) + row)*HW2;
  #pragma unroll
  for (int j = 0; j < 5; ++j) Krow[t + 64*j] = stage[w][t + 64*j];
}

// ---------- B: column FFT + mask*scale + column IFFT, in place on K ----------
__global__ __launch_bounds__(256) void k_colfft_mask(
    float2* __restrict__ K, const float* __restrict__ mask,
    const float2* __restrict__ twg, int b0) {
  __shared__ float re[320][17];   // pad col 16 doubles as twiddle-re table
  __shared__ float im[320][17];   // pad col 16 doubles as twiddle-im table
  __shared__ float mk[320][17];
  int tile = blockIdx.x % 20;
  int c    = (blockIdx.x/20) % NC;
  int bl   = blockIdx.x/(20*NC);
  int b    = b0 + bl;
  int col0 = tile*16;
  float2* Kimg = K + (size_t)(bl*NC + c)*NPIX;
  const float* Mimg = mask + (size_t)b*NPIX;
  for (int k = threadIdx.x; k < 320; k += 256) { float2 w = twg[k]; re[k][16]=w.x; im[k][16]=w.y; }
  for (int idx = threadIdx.x; idx < 320*16; idx += 256) {
    int rw = idx >> 4, cc = idx & 15;
    float2 val = Kimg[(size_t)rw*HW2 + col0 + cc];
    re[rw][cc] = val.x; im[rw][cc] = val.y;
    mk[rw][cc] = Mimg[(size_t)rw*HW2 + col0 + cc] * FSCALE;
  }
  __syncthreads();
  const TwTab tw{ &re[0][16], &im[0][16], 17 };
  int t = threadIdx.x & 63, w = threadIdx.x >> 6, rt = rev6(t);
  float2 v[5];
  for (int ci = 0; ci < 4; ++ci) {
    int col = w*4 + ci;   // each wave owns 4 private columns
    #pragma unroll
    for (int j = 0; j < 5; ++j) v[j] = make_float2(re[t+64*j][col], im[t+64*j][col]);
    fft320_fwd(v, t, tw);
    #pragma unroll
    for (int q = 0; q < 5; ++q) v[q] = cscale(v[q], mk[5*rt+q][col]);
    fft320_inv(v, t, tw);
    #pragma unroll
    for (int j = 0; j < 5; ++j) { re[t+64*j][col] = v[j].x; im[t+64*j][col] = v[j].y; }
  }
  __syncthreads();
  for (int idx = threadIdx.x; idx < 320*16; idx += 256) {
    int rw = idx >> 4, cc = idx & 15;
    Kimg[(size_t)rw*HW2 + col0 + cc] = make_float2(re[rw][cc], im[rw][cc]);
  }
}

// ---------- C: inverse row FFT + sum_c conj(csm)*S + mu*p -> q ----------
__global__ __launch_bounds__(256) void k_irowfft_combine(
    const float2* __restrict__ K, const float* __restrict__ csr,
    const float* __restrict__ csi, const float2* __restrict__ pv,
    float2* __restrict__ qv, const float* __restrict__ mu,
    const float2* __restrict__ twg, int b0) {
  __shared__ float twre[320], twim[320];
  __shared__ float2 rows[4][320];
  for (int i = threadIdx.x; i < 320; i += 256) { float2 w = twg[i]; twre[i]=w.x; twim[i]=w.y; }
  __syncthreads();
  const TwTab tw{twre, twim, 1};
  int row = blockIdx.x % HW2;
  int bl  = blockIdx.x / HW2;
  int b   = b0 + bl;
  int t = threadIdx.x & 63, w = threadIdx.x >> 6, rt = rev6(t);
  float sgn = ((row + t) & 1) ? -1.f : 1.f;
  float2 acc[5];
  #pragma unroll
  for (int j = 0; j < 5; ++j) acc[j] = make_float2(0.f, 0.f);
  for (int c = w; c < NC; c += 4) {
    const float2* Krow = K + ((size_t)((bl*NC + c)*HW2) + row)*HW2;
    float2 v[5];
    #pragma unroll
    for (int q5 = 0; q5 < 5; ++q5) v[q5] = Krow[5*t + q5];     // contiguous 40B/lane
    #pragma unroll
    for (int q5 = 0; q5 < 5; ++q5) v[q5] = shfl2(v[q5], rt);   // -> lane t holds Y[5*rev(t)+q]
    fft320_inv(v, t, tw);
    size_t cs = ((size_t)((b*NC + c)*HW2) + row)*HW2;
    #pragma unroll
    for (int j = 0; j < 5; ++j) {
      int n = t + 64*j;
      float2 cv = make_float2(csr[cs+n], csi[cs+n]);
      acc[j] = cadd(acc[j], cmulc(v[j], cv));
    }
  }
  #pragma unroll
  for (int j = 0; j < 5; ++j) rows[w][t+64*j] = cscale(acc[j], sgn);
  __syncthreads();
  float m = mu[0];
  const float* pf = (const float*)(pv + ((size_t)(b*HW2) + row)*HW2);
  float*       qf = (float*)(qv + ((size_t)(b*HW2) + row)*HW2);
  const float* rf = (const float*)rows;
  for (int i = threadIdx.x; i < 640; i += 256) {
    float s = rf[i] + rf[640+i] + rf[1280+i] + rf[1920+i];
    qf[i] = s + m * pf[i];
  }
}

// ---------- reductions & CG scalar kernels ----------
__global__ void k_dot_rr(const float2* __restrict__ r, float2* partials) {
  float s = 0.f;
  for (int i = blockIdx.x*blockDim.x + threadIdx.x; i < NVEC; i += gridDim.x*blockDim.x) {
    float2 v = r[i]; s += v.x*v.x + v.y*v.y;
  }
  __shared__ float buf[4];
  for (int off = 32; off; off >>= 1) s += __shfl_down(s, off, 64);
  int w = threadIdx.x >> 6, t = threadIdx.x & 63;
  if (t == 0) buf[w] = s;
  __syncthreads();
  if (threadIdx.x == 0) partials[blockIdx.x] = make_float2(buf[0]+buf[1]+buf[2]+buf[3], 0.f);
}
__global__ void k_rr_finish(const float2* __restrict__ partials, float2* scal) {
  float s = 0.f;
  for (int i = threadIdx.x; i < 256; i += blockDim.x) s += partials[i].x;
  __shared__ float buf[4];
  for (int off = 32; off; off >>= 1) s += __shfl_down(s, off, 64);
  int w = threadIdx.x >> 6, t = threadIdx.x & 63;
  if (t == 0) buf[w] = s;
  __syncthreads();
  if (threadIdx.x == 0) scal[0] = make_float2(buf[0]+buf[1]+buf[2]+buf[3], 0.f);
}
__global__ void k_dot_pq(const float2* __restrict__ q, const float2* __restrict__ p, float2* partials) {
  float sr = 0.f, si = 0.f;
  for (int i = blockIdx.x*blockDim.x + threadIdx.x; i < NVEC; i += gridDim.x*blockDim.x) {
    float2 qq = q[i], pp = p[i];
    sr += qq.x*pp.x + qq.y*pp.y;     // q*conj(p)
    si += qq.y*pp.x - qq.x*pp.y;
  }
  __shared__ float2 buf[4];
  for (int off = 32; off; off >>= 1) { sr += __shfl_down(sr, off, 64); si += __shfl_down(si, off, 64); }
  int w = threadIdx.x >> 6, t = threadIdx.x & 63;
  if (t == 0) buf[w] = make_float2(sr, si);
  __syncthreads();
  if (threadIdx.x == 0)
    partials[blockIdx.x] = make_float2(buf[0].x+buf[1].x+buf[2].x+buf[3].x,
                                       buf[0].y+buf[1].y+buf[2].y+buf[3].y);
}
__global__ void k_alpha(const float2* __restrict__ partials, float2* scal) {
  float sr = 0.f, si = 0.f;
  for (int i = threadIdx.x; i < 256; i += blockDim.x) { sr += partials[i].x; si += partials[i].y; }
  __shared__ float2 buf[4];
  for (int off = 32; off; off >>= 1) { sr += __shfl_down(sr, off, 64); si += __shfl_down(si, off, 64); }
  int w = threadIdx.x >> 6, t = threadIdx.x & 63;
  if (t == 0) buf[w] = make_float2(sr, si);
  __syncthreads();
  if (threadIdx.x == 0) {
    float pr = buf[0].x+buf[1].x+buf[2].x+buf[3].x;
    float pi = buf[0].y+buf[1].y+buf[2].y+buf[3].y;
    float rr = scal[0].x;
    float d = pr*pr + pi*pi;
    scal[1] = make_float2(rr*pr/d, -rr*pi/d);   // alpha = rr * conj(pq)/|pq|^2
  }
}
__global__ void k_update(float2* bv, float2* r, const float2* __restrict__ p,
                         const float2* __restrict__ q, const float2* __restrict__ scal,
                         float2* partials) {
  float2 al = scal[1];
  float s = 0.f;
  for (int i = blockIdx.x*blockDim.x + threadIdx.x; i < NVEC; i += gridDim.x*blockDim.x) {
    float2 pp = p[i], qq = q[i];
    bv[i] = cadd(bv[i], cmul(al, pp));
    float2 rn = csub(r[i], cmul(al, qq));
    r[i] = rn;
    s += rn.x*rn.x + rn.y*rn.y;
  }
  __shared__ float buf[4];
  for (int off = 32; off; off >>= 1) s += __shfl_down(s, off, 64);
  int w = threadIdx.x >> 6, t = threadIdx.x & 63;
  if (t == 0) buf[w] = s;
  __syncthreads();
  if (threadIdx.x == 0) partials[blockIdx.x] = make_float2(buf[0]+buf[1]+buf[2]+buf[3], 0.f);
}
__global__ void k_beta(const float2* __restrict__ partials, float2* scal) {
  float s = 0.f;
  for (int i = threadIdx.x; i < 256; i += blockDim.x) s += partials[i].x;
  __shared__ float buf[4];
  for (int off = 32; off; off >>= 1) s += __shfl_down(s, off, 64);
  int w = threadIdx.x >> 6, t = threadIdx.x & 63;
  if (t == 0) buf[w] = s;
  __syncthreads();
  if (threadIdx.x == 0) {
    float rrnew = buf[0]+buf[1]+buf[2]+buf[3];
    float rrold = scal[0].x;
    scal[2] = make_float2(rrnew/rrold, 0.f);
    scal[0] = make_float2(rrnew, 0.f);
  }
}
__global__ void k_pupdate(float2* p, const float2* __restrict__ r, const float2* __restrict__ scal) {
  float be = scal[2].x;
  for (int i = blockIdx.x*blockDim.x + threadIdx.x; i < NVEC; i += gridDim.x*blockDim.x)
    p[i] = cadd(r[i], cscale(p[i], be));
}
__global__ void k_output(const float2* __restrict__ bv, float* __restrict__ out) {
  int i = blockIdx.x*blockDim.x + threadIdx.x;
  if (i >= NVEC) return;
  int b = i / NPIX, hw = i % NPIX;
  float2 v = bv[i];
  out[(size_t)(b*2+0)*NPIX + hw] = v.x;
  out[(size_t)(b*2+1)*NPIX + hw] = v.y;
}

// ---------- host ----------
extern "C" void kernel_launch(void* const* d_in, const int* in_sizes, int n_in,
                              void* d_out, int out_size, void* d_ws, size_t ws_size,
                              hipStream_t stream) {
  const float* us  = (const float*)d_in[0];
  const float* rec = (const float*)d_in[1];
  const float* msk = (const float*)d_in[2];
  const float* csr = (const float*)d_in[3];
  const float* csi = (const float*)d_in[4];
  const float* mu  = (const float*)d_in[5];
  float* out = (float*)d_out;

  const size_t vecB = (size_t)NVEC * 8;
  // batch chunk: K scratch = nb*NC*NPIX complex; shrink nb if ws too small
  int nb = NB;
  while (nb > 1 && ((size_t)nb*NC*NPIX*8 + 4*vecB + 320*8 + 256*8 + 64) > ws_size) nb >>= 1;

  char* w = (char*)d_ws; size_t off = 0;
  float2* K        = (float2*)(w + off); off += (size_t)nb*NC*NPIX*8;
  float2* rv       = (float2*)(w + off); off += vecB;
  float2* pv       = (float2*)(w + off); off += vecB;
  float2* bv       = (float2*)(w + off); off += vecB;
  float2* qv       = (float2*)(w + off); off += vecB;
  float2* twg      = (float2*)(w + off); off += 320*8;
  float2* partials = (float2*)(w + off); off += 256*8;
  float2* scal     = (float2*)(w + off);

  k_twiddle<<<dim3(2), dim3(256), 0, stream>>>(twg);
  k_init<<<dim3(NVEC/256), dim3(256), 0, stream>>>(us, rec, mu, rv, pv, bv);
  k_dot_rr<<<dim3(256), dim3(256), 0, stream>>>(rv, partials);
  k_rr_finish<<<dim3(1), dim3(256), 0, stream>>>(partials, scal);

  for (int it = 0; it < CGI; ++it) {
    for (int b0 = 0; b0 < NB; b0 += nb) {
      k_proj_rowfft    <<<dim3(nb*NC*HW2/4), dim3(256), 0, stream>>>(pv, csr, csi, K, twg, b0);
      k_colfft_mask    <<<dim3(nb*NC*20),    dim3(256), 0, stream>>>(K, msk, twg, b0);
      k_irowfft_combine<<<dim3(nb*HW2),      dim3(256), 0, stream>>>(K, csr, csi, pv, qv, mu, twg, b0);
    }
    k_dot_pq <<<dim3(256), dim3(256), 0, stream>>>(qv, pv, partials);
    k_alpha  <<<dim3(1),   dim3(256), 0, stream>>>(partials, scal);
    k_update <<<dim3(256), dim3(256), 0, stream>>>(bv, rv, pv, qv, scal, partials);
    k_beta   <<<dim3(1),   dim3(256), 0, stream>>>(partials, scal);
    k_pupdate<<<dim3(256), dim3(256), 0, stream>>>(pv, rv, scal);
  }
  k_output<<<dim3(NVEC/256), dim3(256), 0, stream>>>(bv, out);
}

// Round 5
// 1948.955 us; speedup vs baseline: 1.2557x; 1.2557x over previous
//
#include <hip/hip_runtime.h>

#define HW2 320
#define NB 8
#define NC 16
#define NPIX (HW2*HW2)        // 102400
#define NVEC (NB*NPIX)        // 819200
#define CGI 10
#define FSCALE (1.0f/102400.0f)  // ortho fwd (1/320) * ortho inv (1/320)

// ---------- complex helpers ----------
__device__ inline float2 cadd(float2 a, float2 b){return make_float2(a.x+b.x, a.y+b.y);}
__device__ inline float2 csub(float2 a, float2 b){return make_float2(a.x-b.x, a.y-b.y);}
__device__ inline float2 cmul(float2 a, float2 b){return make_float2(a.x*b.x-a.y*b.y, a.x*b.y+a.y*b.x);}
__device__ inline float2 cmulc(float2 a, float2 b){return make_float2(a.x*b.x+a.y*b.y, a.y*b.x-a.x*b.y);} // a*conj(b)
__device__ inline float2 cscale(float2 a, float s){return make_float2(a.x*s, a.y*s);}
__device__ inline int rev6(int t){ return (int)(__brev((unsigned)t) >> 26); }
__device__ inline float2 shflx2(float2 a, int m){ return make_float2(__shfl_xor(a.x,m,64), __shfl_xor(a.y,m,64)); }
__device__ inline float2 shfl2(float2 a, int l){ return make_float2(__shfl(a.x,l,64), __shfl(a.y,l,64)); }

// ---------- radix-5 (in registers). DIR=-1 fwd, +1 inv. Unnormalized. ----------
template<int DIR>
__device__ inline void radix5(float2 (&v)[5]) {
  const float c1 = 0.30901699437494745f, s1 = 0.9510565162951535f;
  const float c2 = -0.8090169943749473f, s2 = 0.5877852522924731f;
  float2 t1 = cadd(v[1], v[4]), t2 = csub(v[1], v[4]);
  float2 t3 = cadd(v[2], v[3]), t4 = csub(v[2], v[3]);
  float2 y0 = cadd(v[0], cadd(t1, t3));
  float2 a1 = make_float2(v[0].x + c1*t1.x + c2*t3.x, v[0].y + c1*t1.y + c2*t3.y);
  float2 a2 = make_float2(v[0].x + c2*t1.x + c1*t3.x, v[0].y + c2*t1.y + c1*t3.y);
  float2 b1 = make_float2(s1*t2.x + s2*t4.x, s1*t2.y + s2*t4.y);
  float2 b2 = make_float2(s2*t2.x - s1*t4.x, s2*t2.y - s1*t4.y);
  const float sg = (float)DIR;
  float2 ib1 = make_float2(-sg*b1.y, sg*b1.x);
  float2 ib2 = make_float2(-sg*b2.y, sg*b2.x);
  v[0] = y0;
  v[1] = cadd(a1, ib1); v[4] = csub(a1, ib1);
  v[2] = cadd(a2, ib2); v[3] = csub(a2, ib2);
}

// ---------- per-lane register twiddles (from f64-accurate global table) ----------
// tw5[q-1] = w320^{q t}; twh[s] = w320^{5*(t&(h-1))*(32/h)}, h=32>>s
__device__ inline void load_tw(const float2* __restrict__ twg, int t,
                               float2 (&tw5)[4], float2 (&twh)[6]) {
  #pragma unroll
  for (int q = 1; q < 5; ++q) tw5[q-1] = twg[q*t];
  twh[0] = twg[5*(t&31)];
  twh[1] = twg[10*(t&15)];
  twh[2] = twg[20*(t&7)];
  twh[3] = twg[40*(t&3)];
  twh[4] = twg[80*(t&1)];
  twh[5] = make_float2(1.f, 0.f);
}

// ---------- 320-pt FFT across one wave, NCOL interleaved columns ----------
// fwd: input  v[k][j] = x[t+64j]  ->  output v[k][q] = X[5*rev6(t)+q]
template<int NCOL>
__device__ inline void fft320_fwd_r(float2 (&v)[NCOL][5], int t,
                                    const float2 (&tw5)[4], const float2 (&twh)[6]) {
  #pragma unroll
  for (int k = 0; k < NCOL; ++k) radix5<-1>(v[k]);
  #pragma unroll
  for (int q = 1; q < 5; ++q)
    #pragma unroll
    for (int k = 0; k < NCOL; ++k) v[k][q] = cmul(v[k][q], tw5[q-1]);
  #pragma unroll
  for (int s = 0; s < 6; ++s) {
    const int h = 32 >> s;
    const bool up = (t & h) != 0;
    const float2 w = twh[s];
    #pragma unroll
    for (int q = 0; q < 5; ++q)
      #pragma unroll
      for (int k = 0; k < NCOL; ++k) {
        float2 o = shflx2(v[k][q], h);
        v[k][q] = up ? cmul(csub(o, v[k][q]), w) : cadd(v[k][q], o);
      }
  }
}
// inv (unnormalized): input v[k][q] = Y[5*rev6(t)+q] -> output v[k][j] = z[t+64j]
template<int NCOL>
__device__ inline void fft320_inv_r(float2 (&v)[NCOL][5], int t,
                                    const float2 (&tw5)[4], const float2 (&twh)[6]) {
  #pragma unroll
  for (int s = 5; s >= 0; --s) {
    const int h = 32 >> s;
    const bool up = (t & h) != 0;
    const float2 wc = make_float2(twh[s].x, -twh[s].y);
    #pragma unroll
    for (int q = 0; q < 5; ++q)
      #pragma unroll
      for (int k = 0; k < NCOL; ++k) {
        float2 mine = up ? cmul(v[k][q], wc) : v[k][q];
        float2 o = shflx2(mine, h);
        v[k][q] = up ? csub(o, mine) : cadd(mine, o);
      }
  }
  #pragma unroll
  for (int q = 1; q < 5; ++q)
    #pragma unroll
    for (int k = 0; k < NCOL; ++k) v[k][q] = cmulc(v[k][q], tw5[q-1]);
  #pragma unroll
  for (int k = 0; k < NCOL; ++k) radix5<1>(v[k]);
}

// ---------- twiddle table init (double precision trig) ----------
__global__ void k_twiddle(float2* tw) {
  int m = blockIdx.x*blockDim.x + threadIdx.x;
  if (m < 320) {
    double a = -2.0 * 3.14159265358979323846 * (double)m / 320.0;
    tw[m] = make_float2((float)cos(a), (float)sin(a));
  }
}

// ---------- r = us + mu*rec ; p = r ; b = 0  (planar -> interleaved) ----------
__global__ void k_init(const float* __restrict__ us, const float* __restrict__ rec,
                       const float* __restrict__ mu,
                       float2* r, float2* p, float2* bv) {
  int i = blockIdx.x*blockDim.x + threadIdx.x;
  if (i >= NVEC) return;
  float m = mu[0];
  int b = i / NPIX, hw = i % NPIX;
  float re = us[(size_t)(b*2+0)*NPIX + hw] + m * rec[(size_t)(b*2+0)*NPIX + hw];
  float im = us[(size_t)(b*2+1)*NPIX + hw] + m * rec[(size_t)(b*2+1)*NPIX + hw];
  float2 v = make_float2(re, im);
  r[i] = v; p[i] = v; bv[i] = make_float2(0.f, 0.f);
}

// ---------- A: coil-project (p*csm*S) + forward row FFT -> K ----------
__global__ __launch_bounds__(256) void k_proj_rowfft(
    const float2* __restrict__ pv, const float* __restrict__ csr,
    const float* __restrict__ csi, float2* __restrict__ K,
    const float2* __restrict__ twg, int b0) {
  __shared__ float2 stage[4][320];
  int t = threadIdx.x & 63, w = threadIdx.x >> 6, rt = rev6(t);
  float2 tw5[4], twh[6];
  load_tw(twg, t, tw5, twh);
  int wid = blockIdx.x*4 + w;
  int row = wid % HW2;
  int c   = (wid / HW2) % NC;
  int bl  = wid / (HW2*NC);
  int b   = b0 + bl;
  const float2* prow = pv + ((size_t)(b*HW2) + row)*HW2;
  size_t cs = ((size_t)((b*NC + c)*HW2) + row)*HW2;
  float sgn = ((row + t) & 1) ? -1.f : 1.f;   // (-1)^{row+n}, n=t+64j
  float2 v[1][5];
  #pragma unroll
  for (int j = 0; j < 5; ++j) {
    int n = t + 64*j;
    float2 cv = make_float2(csr[cs+n], csi[cs+n]);
    v[0][j] = cscale(cmul(prow[n], cv), sgn);
  }
  fft320_fwd_r<1>(v, t, tw5, twh);
  #pragma unroll
  for (int q = 0; q < 5; ++q) stage[w][5*rt + q] = v[0][q];   // wave-local
  float2* Krow = K + ((size_t)((bl*NC + c)*HW2) + row)*HW2;
  #pragma unroll
  for (int j = 0; j < 5; ++j) Krow[t + 64*j] = stage[w][t + 64*j];
}

// ---------- B: column FFT + mask*scale + column IFFT, in place on K ----------
// 512 threads = 8 waves; each wave owns 2 columns, processed interleaved (ILP=2).
// LDS: re/im planes [320][17] + u8 mask [320][16] = 48.6 KB.
// __launch_bounds__(512,4): VGPR cap 128 (no spill risk) -> 2 blocks/CU = 16 waves/CU.
__global__ __launch_bounds__(512, 4) void k_colfft_mask(
    float2* __restrict__ K, const float* __restrict__ mask,
    const float2* __restrict__ twg, int b0) {
  __shared__ float re[320][17];
  __shared__ float im[320][17];
  __shared__ unsigned char mk8[320][16];
  int tile = blockIdx.x % 20;
  int c    = (blockIdx.x/20) % NC;
  int bl   = blockIdx.x/(20*NC);
  int b    = b0 + bl;
  int col0 = tile*16;
  float2* Kimg = K + (size_t)(bl*NC + c)*NPIX;
  const float* Mimg = mask + (size_t)b*NPIX;
  int t = threadIdx.x & 63, w = threadIdx.x >> 6, rt = rev6(t);
  float2 tw5[4], twh[6];
  load_tw(twg, t, tw5, twh);
  for (int idx = threadIdx.x; idx < 320*16; idx += 512) {
    int rw = idx >> 4, cc = idx & 15;
    float2 val = Kimg[(size_t)rw*HW2 + col0 + cc];
    re[rw][cc] = val.x; im[rw][cc] = val.y;
    mk8[rw][cc] = (unsigned char)(Mimg[(size_t)rw*HW2 + col0 + cc] != 0.f);
  }
  __syncthreads();
  const int colA = w*2, colB = w*2 + 1;
  float2 v[2][5];
  #pragma unroll
  for (int j = 0; j < 5; ++j) {
    v[0][j] = make_float2(re[t+64*j][colA], im[t+64*j][colA]);
    v[1][j] = make_float2(re[t+64*j][colB], im[t+64*j][colB]);
  }
  fft320_fwd_r<2>(v, t, tw5, twh);
  #pragma unroll
  for (int q = 0; q < 5; ++q) {
    int rowk = 5*rt + q;
    float m0 = mk8[rowk][colA] ? FSCALE : 0.f;
    float m1 = mk8[rowk][colB] ? FSCALE : 0.f;
    v[0][q] = cscale(v[0][q], m0);
    v[1][q] = cscale(v[1][q], m1);
  }
  fft320_inv_r<2>(v, t, tw5, twh);
  #pragma unroll
  for (int j = 0; j < 5; ++j) {
    re[t+64*j][colA] = v[0][j].x; im[t+64*j][colA] = v[0][j].y;
    re[t+64*j][colB] = v[1][j].x; im[t+64*j][colB] = v[1][j].y;
  }
  __syncthreads();
  for (int idx = threadIdx.x; idx < 320*16; idx += 512) {
    int rw = idx >> 4, cc = idx & 15;
    Kimg[(size_t)rw*HW2 + col0 + cc] = make_float2(re[rw][cc], im[rw][cc]);
  }
}

// ---------- C: inverse row FFT + sum_c conj(csm)*S + mu*p -> q ----------
// 2 coils interleaved per wave iteration (ILP=2).
__global__ __launch_bounds__(256) void k_irowfft_combine(
    const float2* __restrict__ K, const float* __restrict__ csr,
    const float* __restrict__ csi, const float2* __restrict__ pv,
    float2* __restrict__ qv, const float* __restrict__ mu,
    const float2* __restrict__ twg, int b0) {
  __shared__ float2 rows[4][320];
  int t = threadIdx.x & 63, w = threadIdx.x >> 6, rt = rev6(t);
  float2 tw5[4], twh[6];
  load_tw(twg, t, tw5, twh);
  int row = blockIdx.x % HW2;
  int bl  = blockIdx.x / HW2;
  int b   = b0 + bl;
  float sgn = ((row + t) & 1) ? -1.f : 1.f;
  float2 acc[5];
  #pragma unroll
  for (int j = 0; j < 5; ++j) acc[j] = make_float2(0.f, 0.f);
  #pragma unroll
  for (int half = 0; half < 2; ++half) {
    int c0 = w + 8*half;               // coils c0 and c0+4
    const float2* Kr0 = K + ((size_t)((bl*NC + c0)*HW2) + row)*HW2;
    const float2* Kr1 = Kr0 + (size_t)4*NPIX;
    float2 v[2][5];
    #pragma unroll
    for (int q = 0; q < 5; ++q) { v[0][q] = Kr0[5*t+q]; v[1][q] = Kr1[5*t+q]; }
    #pragma unroll
    for (int q = 0; q < 5; ++q) { v[0][q] = shfl2(v[0][q], rt); v[1][q] = shfl2(v[1][q], rt); }
    fft320_inv_r<2>(v, t, tw5, twh);
    size_t cs0 = ((size_t)((b*NC + c0)*HW2) + row)*HW2;
    size_t cs1 = cs0 + (size_t)4*NPIX;
    #pragma unroll
    for (int j = 0; j < 5; ++j) {
      int n = t + 64*j;
      float2 cv0 = make_float2(csr[cs0+n], csi[cs0+n]);
      float2 cv1 = make_float2(csr[cs1+n], csi[cs1+n]);
      acc[j] = cadd(acc[j], cadd(cmulc(v[0][j], cv0), cmulc(v[1][j], cv1)));
    }
  }
  #pragma unroll
  for (int j = 0; j < 5; ++j) rows[w][t+64*j] = cscale(acc[j], sgn);
  __syncthreads();
  float m = mu[0];
  const float* pf = (const float*)(pv + ((size_t)(b*HW2) + row)*HW2);
  float*       qf = (float*)(qv + ((size_t)(b*HW2) + row)*HW2);
  const float* rf = (const float*)rows;
  for (int i = threadIdx.x; i < 640; i += 256) {
    float s = rf[i] + rf[640+i] + rf[1280+i] + rf[1920+i];
    qf[i] = s + m * pf[i];
  }
}

// ---------- reductions & CG scalar kernels (float4-vectorized) ----------
__global__ void k_dot_rr(const float4* __restrict__ r, float2* partials) {
  float s = 0.f;
  for (int i = blockIdx.x*blockDim.x + threadIdx.x; i < NVEC/2; i += gridDim.x*blockDim.x) {
    float4 v = r[i]; s += v.x*v.x + v.y*v.y + v.z*v.z + v.w*v.w;
  }
  __shared__ float buf[4];
  for (int off = 32; off; off >>= 1) s += __shfl_down(s, off, 64);
  int w = threadIdx.x >> 6, t = threadIdx.x & 63;
  if (t == 0) buf[w] = s;
  __syncthreads();
  if (threadIdx.x == 0) partials[blockIdx.x] = make_float2(buf[0]+buf[1]+buf[2]+buf[3], 0.f);
}
__global__ void k_rr_finish(const float2* __restrict__ partials, float2* scal) {
  float s = 0.f;
  for (int i = threadIdx.x; i < 256; i += blockDim.x) s += partials[i].x;
  __shared__ float buf[4];
  for (int off = 32; off; off >>= 1) s += __shfl_down(s, off, 64);
  int w = threadIdx.x >> 6, t = threadIdx.x & 63;
  if (t == 0) buf[w] = s;
  __syncthreads();
  if (threadIdx.x == 0) scal[0] = make_float2(buf[0]+buf[1]+buf[2]+buf[3], 0.f);
}
__global__ void k_dot_pq(const float4* __restrict__ q, const float4* __restrict__ p, float2* partials) {
  float sr = 0.f, si = 0.f;
  for (int i = blockIdx.x*blockDim.x + threadIdx.x; i < NVEC/2; i += gridDim.x*blockDim.x) {
    float4 qq = q[i], pp = p[i];
    sr += qq.x*pp.x + qq.y*pp.y + qq.z*pp.z + qq.w*pp.w;   // q*conj(p)
    si += qq.y*pp.x - qq.x*pp.y + qq.w*pp.z - qq.z*pp.w;
  }
  __shared__ float2 buf[4];
  for (int off = 32; off; off >>= 1) { sr += __shfl_down(sr, off, 64); si += __shfl_down(si, off, 64); }
  int w = threadIdx.x >> 6, t = threadIdx.x & 63;
  if (t == 0) buf[w] = make_float2(sr, si);
  __syncthreads();
  if (threadIdx.x == 0)
    partials[blockIdx.x] = make_float2(buf[0].x+buf[1].x+buf[2].x+buf[3].x,
                                       buf[0].y+buf[1].y+buf[2].y+buf[3].y);
}
__global__ void k_alpha(const float2* __restrict__ partials, float2* scal) {
  float sr = 0.f, si = 0.f;
  for (int i = threadIdx.x; i < 256; i += blockDim.x) { sr += partials[i].x; si += partials[i].y; }
  __shared__ float2 buf[4];
  for (int off = 32; off; off >>= 1) { sr += __shfl_down(sr, off, 64); si += __shfl_down(si, off, 64); }
  int w = threadIdx.x >> 6, t = threadIdx.x & 63;
  if (t == 0) buf[w] = make_float2(sr, si);
  __syncthreads();
  if (threadIdx.x == 0) {
    float pr = buf[0].x+buf[1].x+buf[2].x+buf[3].x;
    float pi = buf[0].y+buf[1].y+buf[2].y+buf[3].y;
    float rr = scal[0].x;
    float d = pr*pr + pi*pi;
    scal[1] = make_float2(rr*pr/d, -rr*pi/d);   // alpha = rr * conj(pq)/|pq|^2
  }
}
__global__ void k_update(float4* bv, float4* r, const float4* __restrict__ p,
                         const float4* __restrict__ q, const float2* __restrict__ scal,
                         float2* partials) {
  float2 al = scal[1];
  float s = 0.f;
  for (int i = blockIdx.x*blockDim.x + threadIdx.x; i < NVEC/2; i += gridDim.x*blockDim.x) {
    float4 pp = p[i], qq = q[i], bb = bv[i], rr = r[i];
    bb.x += al.x*pp.x - al.y*pp.y;  bb.y += al.x*pp.y + al.y*pp.x;
    bb.z += al.x*pp.z - al.y*pp.w;  bb.w += al.x*pp.w + al.y*pp.z;
    bv[i] = bb;
    rr.x -= al.x*qq.x - al.y*qq.y;  rr.y -= al.x*qq.y + al.y*qq.x;
    rr.z -= al.x*qq.z - al.y*qq.w;  rr.w -= al.x*qq.w + al.y*qq.z;
    r[i] = rr;
    s += rr.x*rr.x + rr.y*rr.y + rr.z*rr.z + rr.w*rr.w;
  }
  __shared__ float buf[4];
  for (int off = 32; off; off >>= 1) s += __shfl_down(s, off, 64);
  int w = threadIdx.x >> 6, t = threadIdx.x & 63;
  if (t == 0) buf[w] = s;
  __syncthreads();
  if (threadIdx.x == 0) partials[blockIdx.x] = make_float2(buf[0]+buf[1]+buf[2]+buf[3], 0.f);
}
__global__ void k_beta(const float2* __restrict__ partials, float2* scal) {
  float s = 0.f;
  for (int i = threadIdx.x; i < 256; i += blockDim.x) s += partials[i].x;
  __shared__ float buf[4];
  for (int off = 32; off; off >>= 1) s += __shfl_down(s, off, 64);
  int w = threadIdx.x >> 6, t = threadIdx.x & 63;
  if (t == 0) buf[w] = s;
  __syncthreads();
  if (threadIdx.x == 0) {
    float rrnew = buf[0]+buf[1]+buf[2]+buf[3];
    float rrold = scal[0].x;
    scal[2] = make_float2(rrnew/rrold, 0.f);
    scal[0] = make_float2(rrnew, 0.f);
  }
}
__global__ void k_pupdate(float4* p, const float4* __restrict__ r, const float2* __restrict__ scal) {
  float be = scal[2].x;
  for (int i = blockIdx.x*blockDim.x + threadIdx.x; i < NVEC/2; i += gridDim.x*blockDim.x) {
    float4 pp = p[i], rr = r[i];
    pp.x = rr.x + be*pp.x; pp.y = rr.y + be*pp.y;
    pp.z = rr.z + be*pp.z; pp.w = rr.w + be*pp.w;
    p[i] = pp;
  }
}
__global__ void k_output(const float2* __restrict__ bv, float* __restrict__ out) {
  int i = blockIdx.x*blockDim.x + threadIdx.x;
  if (i >= NVEC) return;
  int b = i / NPIX, hw = i % NPIX;
  float2 v = bv[i];
  out[(size_t)(b*2+0)*NPIX + hw] = v.x;
  out[(size_t)(b*2+1)*NPIX + hw] = v.y;
}

// ---------- host ----------
extern "C" void kernel_launch(void* const* d_in, const int* in_sizes, int n_in,
                              void* d_out, int out_size, void* d_ws, size_t ws_size,
                              hipStream_t stream) {
  const float* us  = (const float*)d_in[0];
  const float* rec = (const float*)d_in[1];
  const float* msk = (const float*)d_in[2];
  const float* csr = (const float*)d_in[3];
  const float* csi = (const float*)d_in[4];
  const float* mu  = (const float*)d_in[5];
  float* out = (float*)d_out;

  const size_t vecB = (size_t)NVEC * 8;
  int nb = NB;
  while (nb > 1 && ((size_t)nb*NC*NPIX*8 + 4*vecB + 320*8 + 256*8 + 64) > ws_size) nb >>= 1;

  char* w = (char*)d_ws; size_t off = 0;
  float2* K        = (float2*)(w + off); off += (size_t)nb*NC*NPIX*8;
  float2* rv       = (float2*)(w + off); off += vecB;
  float2* pv       = (float2*)(w + off); off += vecB;
  float2* bv       = (float2*)(w + off); off += vecB;
  float2* qv       = (float2*)(w + off); off += vecB;
  float2* twg      = (float2*)(w + off); off += 320*8;
  float2* partials = (float2*)(w + off); off += 256*8;
  float2* scal     = (float2*)(w + off);

  k_twiddle<<<dim3(2), dim3(256), 0, stream>>>(twg);
  k_init<<<dim3(NVEC/256), dim3(256), 0, stream>>>(us, rec, mu, rv, pv, bv);
  k_dot_rr<<<dim3(256), dim3(256), 0, stream>>>((const float4*)rv, partials);
  k_rr_finish<<<dim3(1), dim3(256), 0, stream>>>(partials, scal);

  for (int it = 0; it < CGI; ++it) {
    for (int b0 = 0; b0 < NB; b0 += nb) {
      k_proj_rowfft    <<<dim3(nb*NC*HW2/4), dim3(256), 0, stream>>>(pv, csr, csi, K, twg, b0);
      k_colfft_mask    <<<dim3(nb*NC*20),    dim3(512), 0, stream>>>(K, msk, twg, b0);
      k_irowfft_combine<<<dim3(nb*HW2),      dim3(256), 0, stream>>>(K, csr, csi, pv, qv, mu, twg, b0);
    }
    k_dot_pq <<<dim3(256), dim3(256), 0, stream>>>((const float4*)qv, (const float4*)pv, partials);
    k_alpha  <<<dim3(1),   dim3(256), 0, stream>>>(partials, scal);
    k_update <<<dim3(256), dim3(256), 0, stream>>>((float4*)bv, (float4*)rv, (const float4*)pv,
                                                   (const float4*)qv, scal, partials);
    k_beta   <<<dim3(1),   dim3(256), 0, stream>>>(partials, scal);
    k_pupdate<<<dim3(256), dim3(256), 0, stream>>>((float4*)pv, (const float4*)rv, scal);
  }
  k_output<<<dim3(NVEC/256), dim3(256), 0, stream>>>(bv, out);
}

// Round 7
// 1915.289 us; speedup vs baseline: 1.2778x; 1.0176x over previous
//
#include <hip/hip_runtime.h>

#define HW2 320
#define NB 8
#define NC 16
#define NPIX (HW2*HW2)        // 102400
#define NVEC (NB*NPIX)        // 819200
#define CGI 10
#define FSCALE (1.0f/102400.0f)  // ortho fwd (1/320) * ortho inv (1/320)

// ---------- complex helpers ----------
__device__ inline float2 cadd(float2 a, float2 b){return make_float2(a.x+b.x, a.y+b.y);}
__device__ inline float2 csub(float2 a, float2 b){return make_float2(a.x-b.x, a.y-b.y);}
__device__ inline float2 cmul(float2 a, float2 b){return make_float2(a.x*b.x-a.y*b.y, a.x*b.y+a.y*b.x);}
__device__ inline float2 cmulc(float2 a, float2 b){return make_float2(a.x*b.x+a.y*b.y, a.y*b.x-a.x*b.y);} // a*conj(b)
__device__ inline float2 cscale(float2 a, float s){return make_float2(a.x*s, a.y*s);}
__device__ inline int rev6(int t){ return (int)(__brev((unsigned)t) >> 26); }
__device__ inline float2 shflx2(float2 a, int m){ return make_float2(__shfl_xor(a.x,m,64), __shfl_xor(a.y,m,64)); }
__device__ inline float2 shfl2(float2 a, int l){ return make_float2(__shfl(a.x,l,64), __shfl(a.y,l,64)); }

// ---------- radix-5 (in registers). DIR=-1 fwd, +1 inv. Unnormalized. ----------
template<int DIR>
__device__ inline void radix5(float2 (&v)[5]) {
  const float c1 = 0.30901699437494745f, s1 = 0.9510565162951535f;
  const float c2 = -0.8090169943749473f, s2 = 0.5877852522924731f;
  float2 t1 = cadd(v[1], v[4]), t2 = csub(v[1], v[4]);
  float2 t3 = cadd(v[2], v[3]), t4 = csub(v[2], v[3]);
  float2 y0 = cadd(v[0], cadd(t1, t3));
  float2 a1 = make_float2(v[0].x + c1*t1.x + c2*t3.x, v[0].y + c1*t1.y + c2*t3.y);
  float2 a2 = make_float2(v[0].x + c2*t1.x + c1*t3.x, v[0].y + c2*t1.y + c1*t3.y);
  float2 b1 = make_float2(s1*t2.x + s2*t4.x, s1*t2.y + s2*t4.y);
  float2 b2 = make_float2(s2*t2.x - s1*t4.x, s2*t2.y - s1*t4.y);
  const float sg = (float)DIR;
  float2 ib1 = make_float2(-sg*b1.y, sg*b1.x);
  float2 ib2 = make_float2(-sg*b2.y, sg*b2.x);
  v[0] = y0;
  v[1] = cadd(a1, ib1); v[4] = csub(a1, ib1);
  v[2] = cadd(a2, ib2); v[3] = csub(a2, ib2);
}

// ---------- per-lane register twiddles, pre-selected for uniform butterflies ----------
// tw5[q-1] = w320^{q t};  Wf[s] = (t&(32>>s)) ? w320^{5*(t&(h-1))*(32/h)} : 1 ;  sg[s] = +/-1
__device__ inline void load_tw(const float2* __restrict__ twg, int t,
                               float2 (&tw5)[4], float2 (&Wf)[6], float (&sg)[6]) {
  #pragma unroll
  for (int q = 1; q < 5; ++q) tw5[q-1] = twg[q*t];
  float2 tw[6];
  tw[0] = twg[5*(t&31)];
  tw[1] = twg[10*(t&15)];
  tw[2] = twg[20*(t&7)];
  tw[3] = twg[40*(t&3)];
  tw[4] = twg[80*(t&1)];
  tw[5] = make_float2(1.f, 0.f);
  #pragma unroll
  for (int s = 0; s < 6; ++s) {
    bool up = (t & (32 >> s)) != 0;
    Wf[s] = up ? tw[s] : make_float2(1.f, 0.f);
    sg[s] = up ? -1.f : 1.f;
  }
}

// ---------- 320-pt FFT across one wave, NCOL interleaved columns ----------
// Uniform butterflies: no divergent selects; down-lanes multiply by (1,0).
// fwd: input  v[k][j] = x[t+64j]  ->  output v[k][q] = X[5*rev6(t)+q]
template<int NCOL>
__device__ inline void fft320_fwd_r(float2 (&v)[NCOL][5],
                                    const float2 (&tw5)[4], const float2 (&Wf)[6],
                                    const float (&sg)[6]) {
  #pragma unroll
  for (int k = 0; k < NCOL; ++k) radix5<-1>(v[k]);
  #pragma unroll
  for (int q = 1; q < 5; ++q)
    #pragma unroll
    for (int k = 0; k < NCOL; ++k) v[k][q] = cmul(v[k][q], tw5[q-1]);
  #pragma unroll
  for (int s = 0; s < 6; ++s) {
    const int h = 32 >> s;
    const float2 w = Wf[s];
    const float st = sg[s];
    #pragma unroll
    for (int q = 0; q < 5; ++q)
      #pragma unroll
      for (int k = 0; k < NCOL; ++k) {
        float2 o = shflx2(v[k][q], h);
        float2 tmp = make_float2(fmaf(st, v[k][q].x, o.x), fmaf(st, v[k][q].y, o.y));
        v[k][q] = cmul(tmp, w);
      }
  }
}
// inv (unnormalized): input v[k][q] = Y[5*rev6(t)+q] -> output v[k][j] = z[t+64j]
template<int NCOL>
__device__ inline void fft320_inv_r(float2 (&v)[NCOL][5],
                                    const float2 (&tw5)[4], const float2 (&Wf)[6],
                                    const float (&sg)[6]) {
  #pragma unroll
  for (int s = 5; s >= 0; --s) {
    const int h = 32 >> s;
    const float2 w = Wf[s];
    const float st = sg[s];
    #pragma unroll
    for (int q = 0; q < 5; ++q)
      #pragma unroll
      for (int k = 0; k < NCOL; ++k) {
        float2 mine = cmulc(v[k][q], w);
        float2 o = shflx2(mine, h);
        v[k][q] = make_float2(fmaf(st, mine.x, o.x), fmaf(st, mine.y, o.y));
      }
  }
  #pragma unroll
  for (int q = 1; q < 5; ++q)
    #pragma unroll
    for (int k = 0; k < NCOL; ++k) v[k][q] = cmulc(v[k][q], tw5[q-1]);
  #pragma unroll
  for (int k = 0; k < NCOL; ++k) radix5<1>(v[k]);
}

// ---------- twiddle table init (double precision trig) ----------
__global__ void k_twiddle(float2* tw) {
  int m = blockIdx.x*blockDim.x + threadIdx.x;
  if (m < 320) {
    double a = -2.0 * 3.14159265358979323846 * (double)m / 320.0;
    tw[m] = make_float2((float)cos(a), (float)sin(a));
  }
}

// ---------- r = us + mu*rec ; p = r ; b = 0  (planar -> interleaved) ----------
__global__ void k_init(const float* __restrict__ us, const float* __restrict__ rec,
                       const float* __restrict__ mu,
                       float2* r, float2* p, float2* bv) {
  int i = blockIdx.x*blockDim.x + threadIdx.x;
  if (i >= NVEC) return;
  float m = mu[0];
  int b = i / NPIX, hw = i % NPIX;
  float re = us[(size_t)(b*2+0)*NPIX + hw] + m * rec[(size_t)(b*2+0)*NPIX + hw];
  float im = us[(size_t)(b*2+1)*NPIX + hw] + m * rec[(size_t)(b*2+1)*NPIX + hw];
  float2 v = make_float2(re, im);
  r[i] = v; p[i] = v; bv[i] = make_float2(0.f, 0.f);
}

// ---------- A: coil-project (p*csm*S) + forward row FFT -> K ----------
// 2 adjacent rows per wave (ILP=2). 4 waves/block -> 8 rows/block.
__global__ __launch_bounds__(256) void k_proj_rowfft(
    const float2* __restrict__ pv, const float* __restrict__ csr,
    const float* __restrict__ csi, float2* __restrict__ K,
    const float2* __restrict__ twg, int b0) {
  __shared__ float2 stage[8][320];
  int t = threadIdx.x & 63, w = threadIdx.x >> 6, rt = rev6(t);
  float2 tw5[4], Wf[6]; float sg[6];
  load_tw(twg, t, tw5, Wf, sg);
  int wid = blockIdx.x*4 + w;
  int rp  = wid % (HW2/2);           // row-pair index
  int c   = (wid / (HW2/2)) % NC;
  int bl  = wid / ((HW2/2)*NC);
  int b   = b0 + bl;
  int row0 = rp*2;
  const float2* prow = pv + ((size_t)(b*HW2) + row0)*HW2;
  size_t cs = ((size_t)((b*NC + c)*HW2) + row0)*HW2;
  float sgn0 = ((row0 + t) & 1) ? -1.f : 1.f;   // (-1)^{row+n}, n=t+64j
  float sgn1 = -sgn0;
  float2 v[2][5];
  #pragma unroll
  for (int j = 0; j < 5; ++j) {
    int n = t + 64*j;
    float2 cv0 = make_float2(csr[cs+n],     csi[cs+n]);
    float2 cv1 = make_float2(csr[cs+HW2+n], csi[cs+HW2+n]);
    v[0][j] = cscale(cmul(prow[n],     cv0), sgn0);
    v[1][j] = cscale(cmul(prow[HW2+n], cv1), sgn1);
  }
  fft320_fwd_r<2>(v, tw5, Wf, sg);
  #pragma unroll
  for (int q = 0; q < 5; ++q) {
    stage[w*2+0][5*rt + q] = v[0][q];   // wave-local reorder
    stage[w*2+1][5*rt + q] = v[1][q];
  }
  float2* Krow = K + ((size_t)((bl*NC + c)*HW2) + row0)*HW2;
  #pragma unroll
  for (int j = 0; j < 5; ++j) {
    Krow[t + 64*j]       = stage[w*2+0][t + 64*j];
    Krow[HW2 + t + 64*j] = stage[w*2+1][t + 64*j];
  }
}

// ---------- B: column FFT + mask*scale + column IFFT, in place on K ----------
// 512 threads = 8 waves; each wave owns 2 columns, interleaved (ILP=2).
// LDS: re/im [320][17] + u8 mask [320][20] (pad 20 -> 2-way banks) = 48.75 KB -> 3 blocks/CU.
__global__ __launch_bounds__(512, 4) void k_colfft_mask(
    float2* __restrict__ K, const float* __restrict__ mask,
    const float2* __restrict__ twg, int b0) {
  __shared__ float re[320][17];
  __shared__ float im[320][17];
  __shared__ unsigned char mk8[320][20];
  int tile = blockIdx.x % 20;
  int c    = (blockIdx.x/20) % NC;
  int bl   = blockIdx.x/(20*NC);
  int b    = b0 + bl;
  int col0 = tile*16;
  float2* Kimg = K + (size_t)(bl*NC + c)*NPIX;
  const float* Mimg = mask + (size_t)b*NPIX;
  int t = threadIdx.x & 63, w = threadIdx.x >> 6, rt = rev6(t);
  float2 tw5[4], Wf[6]; float sg[6];
  load_tw(twg, t, tw5, Wf, sg);
  for (int idx = threadIdx.x; idx < 320*16; idx += 512) {
    int rw = idx >> 4, cc = idx & 15;
    float2 val = Kimg[(size_t)rw*HW2 + col0 + cc];
    re[rw][cc] = val.x; im[rw][cc] = val.y;
    mk8[rw][cc] = (unsigned char)(Mimg[(size_t)rw*HW2 + col0 + cc] != 0.f);
  }
  __syncthreads();
  const int colA = w*2, colB = w*2 + 1;
  float2 v[2][5];
  #pragma unroll
  for (int j = 0; j < 5; ++j) {
    v[0][j] = make_float2(re[t+64*j][colA], im[t+64*j][colA]);
    v[1][j] = make_float2(re[t+64*j][colB], im[t+64*j][colB]);
  }
  fft320_fwd_r<2>(v, tw5, Wf, sg);
  #pragma unroll
  for (int q = 0; q < 5; ++q) {
    int rowk = 5*rt + q;
    float m0 = mk8[rowk][colA] ? FSCALE : 0.f;
    float m1 = mk8[rowk][colB] ? FSCALE : 0.f;
    v[0][q] = cscale(v[0][q], m0);
    v[1][q] = cscale(v[1][q], m1);
  }
  fft320_inv_r<2>(v, tw5, Wf, sg);
  #pragma unroll
  for (int j = 0; j < 5; ++j) {
    re[t+64*j][colA] = v[0][j].x; im[t+64*j][colA] = v[0][j].y;
    re[t+64*j][colB] = v[1][j].x; im[t+64*j][colB] = v[1][j].y;
  }
  __syncthreads();
  for (int idx = threadIdx.x; idx < 320*16; idx += 512) {
    int rw = idx >> 4, cc = idx & 15;
    Kimg[(size_t)rw*HW2 + col0 + cc] = make_float2(re[rw][cc], im[rw][cc]);
  }
}

// ---------- C: inverse row FFT + sum_c conj(csm)*S + mu*p -> q ----------
// 2 coils interleaved per wave iteration (ILP=2).
__global__ __launch_bounds__(256) void k_irowfft_combine(
    const float2* __restrict__ K, const float* __restrict__ csr,
    const float* __restrict__ csi, const float2* __restrict__ pv,
    float2* __restrict__ qv, const float* __restrict__ mu,
    const float2* __restrict__ twg, int b0) {
  __shared__ float2 rows[4][320];
  int t = threadIdx.x & 63, w = threadIdx.x >> 6, rt = rev6(t);
  float2 tw5[4], Wf[6]; float sg[6];
  load_tw(twg, t, tw5, Wf, sg);
  int row = blockIdx.x % HW2;
  int bl  = blockIdx.x / HW2;
  int b   = b0 + bl;
  float sgn = ((row + t) & 1) ? -1.f : 1.f;
  float2 acc[5];
  #pragma unroll
  for (int j = 0; j < 5; ++j) acc[j] = make_float2(0.f, 0.f);
  #pragma unroll
  for (int half = 0; half < 2; ++half) {
    int c0 = w + 8*half;               // coils c0 and c0+4
    const float2* Kr0 = K + ((size_t)((bl*NC + c0)*HW2) + row)*HW2;
    const float2* Kr1 = Kr0 + (size_t)4*NPIX;
    float2 v[2][5];
    #pragma unroll
    for (int q = 0; q < 5; ++q) { v[0][q] = Kr0[5*t+q]; v[1][q] = Kr1[5*t+q]; }
    #pragma unroll
    for (int q = 0; q < 5; ++q) { v[0][q] = shfl2(v[0][q], rt); v[1][q] = shfl2(v[1][q], rt); }
    fft320_inv_r<2>(v, tw5, Wf, sg);
    size_t cs0 = ((size_t)((b*NC + c0)*HW2) + row)*HW2;
    size_t cs1 = cs0 + (size_t)4*NPIX;
    #pragma unroll
    for (int j = 0; j < 5; ++j) {
      int n = t + 64*j;
      float2 cv0 = make_float2(csr[cs0+n], csi[cs0+n]);
      float2 cv1 = make_float2(csr[cs1+n], csi[cs1+n]);
      acc[j] = cadd(acc[j], cadd(cmulc(v[0][j], cv0), cmulc(v[1][j], cv1)));
    }
  }
  #pragma unroll
  for (int j = 0; j < 5; ++j) rows[w][t+64*j] = cscale(acc[j], sgn);
  __syncthreads();
  float m = mu[0];
  const float* pf = (const float*)(pv + ((size_t)(b*HW2) + row)*HW2);
  float*       qf = (float*)(qv + ((size_t)(b*HW2) + row)*HW2);
  const float* rf = (const float*)rows;
  for (int i = threadIdx.x; i < 640; i += 256) {
    float s = rf[i] + rf[640+i] + rf[1280+i] + rf[1920+i];
    qf[i] = s + m * pf[i];
  }
}

// ---------- reductions & CG scalar kernels (float4-vectorized) ----------
__global__ void k_dot_rr(const float4* __restrict__ r, float2* partials) {
  float s = 0.f;
  for (int i = blockIdx.x*blockDim.x + threadIdx.x; i < NVEC/2; i += gridDim.x*blockDim.x) {
    float4 v = r[i]; s += v.x*v.x + v.y*v.y + v.z*v.z + v.w*v.w;
  }
  __shared__ float buf[4];
  for (int off = 32; off; off >>= 1) s += __shfl_down(s, off, 64);
  int w = threadIdx.x >> 6, t = threadIdx.x & 63;
  if (t == 0) buf[w] = s;
  __syncthreads();
  if (threadIdx.x == 0) partials[blockIdx.x] = make_float2(buf[0]+buf[1]+buf[2]+buf[3], 0.f);
}
__global__ void k_rr_finish(const float2* __restrict__ partials, float2* scal) {
  float s = 0.f;
  for (int i = threadIdx.x; i < 256; i += blockDim.x) s += partials[i].x;
  __shared__ float buf[4];
  for (int off = 32; off; off >>= 1) s += __shfl_down(s, off, 64);
  int w = threadIdx.x >> 6, t = threadIdx.x & 63;
  if (t == 0) buf[w] = s;
  __syncthreads();
  if (threadIdx.x == 0) scal[0] = make_float2(buf[0]+buf[1]+buf[2]+buf[3], 0.f);
}
__global__ void k_dot_pq(const float4* __restrict__ q, const float4* __restrict__ p, float2* partials) {
  float sr = 0.f, si = 0.f;
  for (int i = blockIdx.x*blockDim.x + threadIdx.x; i < NVEC/2; i += gridDim.x*blockDim.x) {
    float4 qq = q[i], pp = p[i];
    sr += qq.x*pp.x + qq.y*pp.y + qq.z*pp.z + qq.w*pp.w;   // q*conj(p)
    si += qq.y*pp.x - qq.x*pp.y + qq.w*pp.z - qq.z*pp.w;
  }
  __shared__ float2 buf[4];
  for (int off = 32; off; off >>= 1) { sr += __shfl_down(sr, off, 64); si += __shfl_down(si, off, 64); }
  int w = threadIdx.x >> 6, t = threadIdx.x & 63;
  if (t == 0) buf[w] = make_float2(sr, si);
  __syncthreads();
  if (threadIdx.x == 0)
    partials[blockIdx.x] = make_float2(buf[0].x+buf[1].x+buf[2].x+buf[3].x,
                                       buf[0].y+buf[1].y+buf[2].y+buf[3].y);
}
__global__ void k_alpha(const float2* __restrict__ partials, float2* scal) {
  float sr = 0.f, si = 0.f;
  for (int i = threadIdx.x; i < 256; i += blockDim.x) { sr += partials[i].x; si += partials[i].y; }
  __shared__ float2 buf[4];
  for (int off = 32; off; off >>= 1) { sr += __shfl_down(sr, off, 64); si += __shfl_down(si, off, 64); }
  int w = threadIdx.x >> 6, t = threadIdx.x & 63;
  if (t == 0) buf[w] = make_float2(sr, si);
  __syncthreads();
  if (threadIdx.x == 0) {
    float pr = buf[0].x+buf[1].x+buf[2].x+buf[3].x;
    float pi = buf[0].y+buf[1].y+buf[2].y+buf[3].y;
    float rr = scal[0].x;
    float d = pr*pr + pi*pi;
    scal[1] = make_float2(rr*pr/d, -rr*pi/d);   // alpha = rr * conj(pq)/|pq|^2
  }
}
__global__ void k_update(float4* bv, float4* r, const float4* __restrict__ p,
                         const float4* __restrict__ q, const float2* __restrict__ scal,
                         float2* partials) {
  float2 al = scal[1];
  float s = 0.f;
  for (int i = blockIdx.x*blockDim.x + threadIdx.x; i < NVEC/2; i += gridDim.x*blockDim.x) {
    float4 pp = p[i], qq = q[i], bb = bv[i], rr = r[i];
    bb.x += al.x*pp.x - al.y*pp.y;  bb.y += al.x*pp.y + al.y*pp.x;
    bb.z += al.x*pp.z - al.y*pp.w;  bb.w += al.x*pp.w + al.y*pp.z;
    bv[i] = bb;
    rr.x -= al.x*qq.x - al.y*qq.y;  rr.y -= al.x*qq.y + al.y*qq.x;
    rr.z -= al.x*qq.z - al.y*qq.w;  rr.w -= al.x*qq.w + al.y*qq.z;
    r[i] = rr;
    s += rr.x*rr.x + rr.y*rr.y + rr.z*rr.z + rr.w*rr.w;
  }
  __shared__ float buf[4];
  for (int off = 32; off; off >>= 1) s += __shfl_down(s, off, 64);
  int w = threadIdx.x >> 6, t = threadIdx.x & 63;
  if (t == 0) buf[w] = s;
  __syncthreads();
  if (threadIdx.x == 0) partials[blockIdx.x] = make_float2(buf[0]+buf[1]+buf[2]+buf[3], 0.f);
}
__global__ void k_beta(const float2* __restrict__ partials, float2* scal) {
  float s = 0.f;
  for (int i = threadIdx.x; i < 256; i += blockDim.x) s += partials[i].x;
  __shared__ float buf[4];
  for (int off = 32; off; off >>= 1) s += __shfl_down(s, off, 64);
  int w = threadIdx.x >> 6, t = threadIdx.x & 63;
  if (t == 0) buf[w] = s;
  __syncthreads();
  if (threadIdx.x == 0) {
    float rrnew = buf[0]+buf[1]+buf[2]+buf[3];
    float rrold = scal[0].x;
    scal[2] = make_float2(rrnew/rrold, 0.f);
    scal[0] = make_float2(rrnew, 0.f);
  }
}
__global__ void k_pupdate(float4* p, const float4* __restrict__ r, const float2* __restrict__ scal) {
  float be = scal[2].x;
  for (int i = blockIdx.x*blockDim.x + threadIdx.x; i < NVEC/2; i += gridDim.x*blockDim.x) {
    float4 pp = p[i], rr = r[i];
    pp.x = rr.x + be*pp.x; pp.y = rr.y + be*pp.y;
    pp.z = rr.z + be*pp.z; pp.w = rr.w + be*pp.w;
    p[i] = pp;
  }
}
__global__ void k_output(const float2* __restrict__ bv, float* __restrict__ out) {
  int i = blockIdx.x*blockDim.x + threadIdx.x;
  if (i >= NVEC) return;
  int b = i / NPIX, hw = i % NPIX;
  float2 v = bv[i];
  out[(size_t)(b*2+0)*NPIX + hw] = v.x;
  out[(size_t)(b*2+1)*NPIX + hw] = v.y;
}

// ---------- host ----------
extern "C" void kernel_launch(void* const* d_in, const int* in_sizes, int n_in,
                              void* d_out, int out_size, void* d_ws, size_t ws_size,
                              hipStream_t stream) {
  const float* us  = (const float*)d_in[0];
  const float* rec = (const float*)d_in[1];
  const float* msk = (const float*)d_in[2];
  const float* csr = (const float*)d_in[3];
  const float* csi = (const float*)d_in[4];
  const float* mu  = (const float*)d_in[5];
  float* out = (float*)d_out;

  const size_t vecB = (size_t)NVEC * 8;
  int nb = NB;
  while (nb > 1 && ((size_t)nb*NC*NPIX*8 + 4*vecB + 320*8 + 256*8 + 64) > ws_size) nb >>= 1;

  char* w = (char*)d_ws; size_t off = 0;
  float2* K        = (float2*)(w + off); off += (size_t)nb*NC*NPIX*8;
  float2* rv       = (float2*)(w + off); off += vecB;
  float2* pv       = (float2*)(w + off); off += vecB;
  float2* bv       = (float2*)(w + off); off += vecB;
  float2* qv       = (float2*)(w + off); off += vecB;
  float2* twg      = (float2*)(w + off); off += 320*8;
  float2* partials = (float2*)(w + off); off += 256*8;
  float2* scal     = (float2*)(w + off);

  k_twiddle<<<dim3(2), dim3(256), 0, stream>>>(twg);
  k_init<<<dim3(NVEC/256), dim3(256), 0, stream>>>(us, rec, mu, rv, pv, bv);
  k_dot_rr<<<dim3(256), dim3(256), 0, stream>>>((const float4*)rv, partials);
  k_rr_finish<<<dim3(1), dim3(256), 0, stream>>>(partials, scal);

  for (int it = 0; it < CGI; ++it) {
    for (int b0 = 0; b0 < NB; b0 += nb) {
      k_proj_rowfft    <<<dim3(nb*NC*(HW2/2)/4), dim3(256), 0, stream>>>(pv, csr, csi, K, twg, b0);
      k_colfft_mask    <<<dim3(nb*NC*20),        dim3(512), 0, stream>>>(K, msk, twg, b0);
      k_irowfft_combine<<<dim3(nb*HW2),          dim3(256), 0, stream>>>(K, csr, csi, pv, qv, mu, twg, b0);
    }
    k_dot_pq <<<dim3(256), dim3(256), 0, stream>>>((const float4*)qv, (const float4*)pv, partials);
    k_alpha  <<<dim3(1),   dim3(256), 0, stream>>>(partials, scal);
    k_update <<<dim3(256), dim3(256), 0, stream>>>((float4*)bv, (float4*)rv, (const float4*)pv,
                                                   (const float4*)qv, scal, partials);
    k_beta   <<<dim3(1),   dim3(256), 0, stream>>>(partials, scal);
    k_pupdate<<<dim3(256), dim3(256), 0, stream>>>((float4*)pv, (const float4*)rv, scal);
  }
  k_output<<<dim3(NVEC/256), dim3(256), 0, stream>>>(bv, out);
}

// Round 8
// 1783.827 us; speedup vs baseline: 1.3719x; 1.0737x over previous
//
#include <hip/hip_runtime.h>

#define HW2 320
#define NB 8
#define NC 16
#define NPIX (HW2*HW2)        // 102400
#define NVEC (NB*NPIX)        // 819200
#define CGI 10
#define FSCALE (1.0f/102400.0f)  // ortho fwd (1/320) * ortho inv (1/320)

// ---------- complex helpers ----------
__device__ inline float2 cadd(float2 a, float2 b){return make_float2(a.x+b.x, a.y+b.y);}
__device__ inline float2 csub(float2 a, float2 b){return make_float2(a.x-b.x, a.y-b.y);}
__device__ inline float2 cmul(float2 a, float2 b){return make_float2(a.x*b.x-a.y*b.y, a.x*b.y+a.y*b.x);}
__device__ inline float2 cmulc(float2 a, float2 b){return make_float2(a.x*b.x+a.y*b.y, a.y*b.x-a.x*b.y);} // a*conj(b)
__device__ inline float2 cscale(float2 a, float s){return make_float2(a.x*s, a.y*s);}
__device__ inline int rev6(int t){ return (int)(__brev((unsigned)t) >> 26); }
__device__ inline float2 shflx2(float2 a, int m){ return make_float2(__shfl_xor(a.x,m,64), __shfl_xor(a.y,m,64)); }
__device__ inline float2 shfl2(float2 a, int l){ return make_float2(__shfl(a.x,l,64), __shfl(a.y,l,64)); }

// ---------- lane-xor exchange, cheapest instruction per distance ----------
// h=1,2: DPP quad_perm (VALU, no LDS). h=4,8,16: ds_swizzle BitMode imm
// (within-32 xor, no addr VGPR, no bank conflicts). h=32: ds_bpermute via shfl.
template<int H>
__device__ inline float2 xsh2t(float2 a) {
  if constexpr (H == 1) {
    return make_float2(
      __int_as_float(__builtin_amdgcn_mov_dpp(__float_as_int(a.x), 0xB1, 0xF, 0xF, true)),
      __int_as_float(__builtin_amdgcn_mov_dpp(__float_as_int(a.y), 0xB1, 0xF, 0xF, true)));
  } else if constexpr (H == 2) {
    return make_float2(
      __int_as_float(__builtin_amdgcn_mov_dpp(__float_as_int(a.x), 0x4E, 0xF, 0xF, true)),
      __int_as_float(__builtin_amdgcn_mov_dpp(__float_as_int(a.y), 0x4E, 0xF, 0xF, true)));
  } else if constexpr (H == 32) {
    return shflx2(a, 32);
  } else {
    constexpr int imm = (H << 10) | 0x1F;   // xor_mask=H, or=0, and=31
    return make_float2(
      __int_as_float(__builtin_amdgcn_ds_swizzle(__float_as_int(a.x), imm)),
      __int_as_float(__builtin_amdgcn_ds_swizzle(__float_as_int(a.y), imm)));
  }
}

// ---------- radix-5 (in registers). DIR=-1 fwd, +1 inv. Unnormalized. ----------
template<int DIR>
__device__ inline void radix5(float2 (&v)[5]) {
  const float c1 = 0.30901699437494745f, s1 = 0.9510565162951535f;
  const float c2 = -0.8090169943749473f, s2 = 0.5877852522924731f;
  float2 t1 = cadd(v[1], v[4]), t2 = csub(v[1], v[4]);
  float2 t3 = cadd(v[2], v[3]), t4 = csub(v[2], v[3]);
  float2 y0 = cadd(v[0], cadd(t1, t3));
  float2 a1 = make_float2(v[0].x + c1*t1.x + c2*t3.x, v[0].y + c1*t1.y + c2*t3.y);
  float2 a2 = make_float2(v[0].x + c2*t1.x + c1*t3.x, v[0].y + c2*t1.y + c1*t3.y);
  float2 b1 = make_float2(s1*t2.x + s2*t4.x, s1*t2.y + s2*t4.y);
  float2 b2 = make_float2(s2*t2.x - s1*t4.x, s2*t2.y - s1*t4.y);
  const float sg = (float)DIR;
  float2 ib1 = make_float2(-sg*b1.y, sg*b1.x);
  float2 ib2 = make_float2(-sg*b2.y, sg*b2.x);
  v[0] = y0;
  v[1] = cadd(a1, ib1); v[4] = csub(a1, ib1);
  v[2] = cadd(a2, ib2); v[3] = csub(a2, ib2);
}

// ---------- per-lane register twiddles, pre-selected for uniform butterflies ----------
// tw5[q-1] = w320^{q t};  Wf[s] for h=32>>s: (t&h) ? w320^{5*(t&(h-1))*(32/h)} : 1 ; sg[s]=+/-1
__device__ inline void load_tw(const float2* __restrict__ twg, int t,
                               float2 (&tw5)[4], float2 (&Wf)[6], float (&sg)[6]) {
  #pragma unroll
  for (int q = 1; q < 5; ++q) tw5[q-1] = twg[q*t];
  float2 tw[6];
  tw[0] = twg[5*(t&31)];
  tw[1] = twg[10*(t&15)];
  tw[2] = twg[20*(t&7)];
  tw[3] = twg[40*(t&3)];
  tw[4] = twg[80*(t&1)];
  tw[5] = make_float2(1.f, 0.f);
  #pragma unroll
  for (int s = 0; s < 6; ++s) {
    bool up = (t & (32 >> s)) != 0;
    Wf[s] = up ? tw[s] : make_float2(1.f, 0.f);
    sg[s] = up ? -1.f : 1.f;
  }
}

// ---------- butterfly stages (uniform FMA form) ----------
template<int H, int NCOL>
__device__ inline void bf_fwd(float2 (&v)[NCOL][5], float2 w, float st) {
  #pragma unroll
  for (int q = 0; q < 5; ++q)
    #pragma unroll
    for (int k = 0; k < NCOL; ++k) {
      float2 o = xsh2t<H>(v[k][q]);
      float2 tmp = make_float2(fmaf(st, v[k][q].x, o.x), fmaf(st, v[k][q].y, o.y));
      v[k][q] = cmul(tmp, w);
    }
}
template<int H, int NCOL>
__device__ inline void bf_inv(float2 (&v)[NCOL][5], float2 w, float st) {
  #pragma unroll
  for (int q = 0; q < 5; ++q)
    #pragma unroll
    for (int k = 0; k < NCOL; ++k) {
      float2 mine = cmulc(v[k][q], w);
      float2 o = xsh2t<H>(mine);
      v[k][q] = make_float2(fmaf(st, mine.x, o.x), fmaf(st, mine.y, o.y));
    }
}

// ---------- 320-pt FFT across one wave, NCOL interleaved columns ----------
// fwd: input  v[k][j] = x[t+64j]  ->  output v[k][q] = X[5*rev6(t)+q]
template<int NCOL>
__device__ inline void fft320_fwd_r(float2 (&v)[NCOL][5],
                                    const float2 (&tw5)[4], const float2 (&Wf)[6],
                                    const float (&sg)[6]) {
  #pragma unroll
  for (int k = 0; k < NCOL; ++k) radix5<-1>(v[k]);
  #pragma unroll
  for (int q = 1; q < 5; ++q)
    #pragma unroll
    for (int k = 0; k < NCOL; ++k) v[k][q] = cmul(v[k][q], tw5[q-1]);
  bf_fwd<32>(v, Wf[0], sg[0]);
  bf_fwd<16>(v, Wf[1], sg[1]);
  bf_fwd< 8>(v, Wf[2], sg[2]);
  bf_fwd< 4>(v, Wf[3], sg[3]);
  bf_fwd< 2>(v, Wf[4], sg[4]);
  bf_fwd< 1>(v, Wf[5], sg[5]);
}
// inv (unnormalized): input v[k][q] = Y[5*rev6(t)+q] -> output v[k][j] = z[t+64j]
template<int NCOL>
__device__ inline void fft320_inv_r(float2 (&v)[NCOL][5],
                                    const float2 (&tw5)[4], const float2 (&Wf)[6],
                                    const float (&sg)[6]) {
  bf_inv< 1>(v, Wf[5], sg[5]);
  bf_inv< 2>(v, Wf[4], sg[4]);
  bf_inv< 4>(v, Wf[3], sg[3]);
  bf_inv< 8>(v, Wf[2], sg[2]);
  bf_inv<16>(v, Wf[1], sg[1]);
  bf_inv<32>(v, Wf[0], sg[0]);
  #pragma unroll
  for (int q = 1; q < 5; ++q)
    #pragma unroll
    for (int k = 0; k < NCOL; ++k) v[k][q] = cmulc(v[k][q], tw5[q-1]);
  #pragma unroll
  for (int k = 0; k < NCOL; ++k) radix5<1>(v[k]);
}

// ---------- twiddle table init (double precision trig) ----------
__global__ void k_twiddle(float2* tw) {
  int m = blockIdx.x*blockDim.x + threadIdx.x;
  if (m < 320) {
    double a = -2.0 * 3.14159265358979323846 * (double)m / 320.0;
    tw[m] = make_float2((float)cos(a), (float)sin(a));
  }
}

// ---------- r = us + mu*rec ; p = r ; b = 0  (planar -> interleaved) ----------
__global__ void k_init(const float* __restrict__ us, const float* __restrict__ rec,
                       const float* __restrict__ mu,
                       float2* r, float2* p, float2* bv) {
  int i = blockIdx.x*blockDim.x + threadIdx.x;
  if (i >= NVEC) return;
  float m = mu[0];
  int b = i / NPIX, hw = i % NPIX;
  float re = us[(size_t)(b*2+0)*NPIX + hw] + m * rec[(size_t)(b*2+0)*NPIX + hw];
  float im = us[(size_t)(b*2+1)*NPIX + hw] + m * rec[(size_t)(b*2+1)*NPIX + hw];
  float2 v = make_float2(re, im);
  r[i] = v; p[i] = v; bv[i] = make_float2(0.f, 0.f);
}

// ---------- A: coil-project (p*csm*S) + forward row FFT -> K ----------
// 2 adjacent rows per wave (ILP=2). 4 waves/block -> 8 rows/block.
__global__ __launch_bounds__(256) void k_proj_rowfft(
    const float2* __restrict__ pv, const float* __restrict__ csr,
    const float* __restrict__ csi, float2* __restrict__ K,
    const float2* __restrict__ twg, int b0) {
  __shared__ float2 stage[8][320];
  int t = threadIdx.x & 63, w = threadIdx.x >> 6, rt = rev6(t);
  float2 tw5[4], Wf[6]; float sg[6];
  load_tw(twg, t, tw5, Wf, sg);
  int wid = blockIdx.x*4 + w;
  int rp  = wid % (HW2/2);           // row-pair index
  int c   = (wid / (HW2/2)) % NC;
  int bl  = wid / ((HW2/2)*NC);
  int b   = b0 + bl;
  int row0 = rp*2;
  const float2* prow = pv + ((size_t)(b*HW2) + row0)*HW2;
  size_t cs = ((size_t)((b*NC + c)*HW2) + row0)*HW2;
  float sgn0 = ((row0 + t) & 1) ? -1.f : 1.f;   // (-1)^{row+n}, n=t+64j
  float sgn1 = -sgn0;
  float2 v[2][5];
  #pragma unroll
  for (int j = 0; j < 5; ++j) {
    int n = t + 64*j;
    float2 cv0 = make_float2(csr[cs+n],     csi[cs+n]);
    float2 cv1 = make_float2(csr[cs+HW2+n], csi[cs+HW2+n]);
    v[0][j] = cscale(cmul(prow[n],     cv0), sgn0);
    v[1][j] = cscale(cmul(prow[HW2+n], cv1), sgn1);
  }
  fft320_fwd_r<2>(v, tw5, Wf, sg);
  #pragma unroll
  for (int q = 0; q < 5; ++q) {
    stage[w*2+0][5*rt + q] = v[0][q];   // wave-local reorder
    stage[w*2+1][5*rt + q] = v[1][q];
  }
  float2* Krow = K + ((size_t)((bl*NC + c)*HW2) + row0)*HW2;
  #pragma unroll
  for (int j = 0; j < 5; ++j) {
    Krow[t + 64*j]       = stage[w*2+0][t + 64*j];
    Krow[HW2 + t + 64*j] = stage[w*2+1][t + 64*j];
  }
}

// ---------- B: column FFT + mask*scale + column IFFT, in place on K ----------
// 512 threads = 8 waves; each wave owns 2 columns, interleaved (ILP=2).
// LDS: float2 tile [320][17] (b64 ops, odd stride) + u8 mask [320][20] = 48.75 KB.
__global__ __launch_bounds__(512, 4) void k_colfft_mask(
    float2* __restrict__ K, const float* __restrict__ mask,
    const float2* __restrict__ twg, int b0) {
  __shared__ float2 kd[320][17];
  __shared__ unsigned char mk8[320][20];
  int tile = blockIdx.x % 20;
  int c    = (blockIdx.x/20) % NC;
  int bl   = blockIdx.x/(20*NC);
  int b    = b0 + bl;
  int col0 = tile*16;
  float2* Kimg = K + (size_t)(bl*NC + c)*NPIX;
  const float* Mimg = mask + (size_t)b*NPIX;
  int t = threadIdx.x & 63, w = threadIdx.x >> 6, rt = rev6(t);
  float2 tw5[4], Wf[6]; float sg[6];
  load_tw(twg, t, tw5, Wf, sg);
  for (int idx = threadIdx.x; idx < 320*16; idx += 512) {
    int rw = idx >> 4, cc = idx & 15;
    kd[rw][cc] = Kimg[(size_t)rw*HW2 + col0 + cc];
    mk8[rw][cc] = (unsigned char)(Mimg[(size_t)rw*HW2 + col0 + cc] != 0.f);
  }
  __syncthreads();
  const int colA = w*2, colB = w*2 + 1;
  float2 v[2][5];
  #pragma unroll
  for (int j = 0; j < 5; ++j) {
    v[0][j] = kd[t+64*j][colA];
    v[1][j] = kd[t+64*j][colB];
  }
  fft320_fwd_r<2>(v, tw5, Wf, sg);
  #pragma unroll
  for (int q = 0; q < 5; ++q) {
    int rowk = 5*rt + q;
    float m0 = mk8[rowk][colA] ? FSCALE : 0.f;
    float m1 = mk8[rowk][colB] ? FSCALE : 0.f;
    v[0][q] = cscale(v[0][q], m0);
    v[1][q] = cscale(v[1][q], m1);
  }
  fft320_inv_r<2>(v, tw5, Wf, sg);
  #pragma unroll
  for (int j = 0; j < 5; ++j) {
    kd[t+64*j][colA] = v[0][j];
    kd[t+64*j][colB] = v[1][j];
  }
  __syncthreads();
  for (int idx = threadIdx.x; idx < 320*16; idx += 512) {
    int rw = idx >> 4, cc = idx & 15;
    Kimg[(size_t)rw*HW2 + col0 + cc] = kd[rw][cc];
  }
}

// ---------- C: inverse row FFT + sum_c conj(csm)*S + mu*p -> q ----------
// 2 coils interleaved per wave iteration (ILP=2).
__global__ __launch_bounds__(256) void k_irowfft_combine(
    const float2* __restrict__ K, const float* __restrict__ csr,
    const float* __restrict__ csi, const float2* __restrict__ pv,
    float2* __restrict__ qv, const float* __restrict__ mu,
    const float2* __restrict__ twg, int b0) {
  __shared__ float2 rows[4][320];
  int t = threadIdx.x & 63, w = threadIdx.x >> 6, rt = rev6(t);
  float2 tw5[4], Wf[6]; float sg[6];
  load_tw(twg, t, tw5, Wf, sg);
  int row = blockIdx.x % HW2;
  int bl  = blockIdx.x / HW2;
  int b   = b0 + bl;
  float sgn = ((row + t) & 1) ? -1.f : 1.f;
  float2 acc[5];
  #pragma unroll
  for (int j = 0; j < 5; ++j) acc[j] = make_float2(0.f, 0.f);
  #pragma unroll
  for (int half = 0; half < 2; ++half) {
    int c0 = w + 8*half;               // coils c0 and c0+4
    const float2* Kr0 = K + ((size_t)((bl*NC + c0)*HW2) + row)*HW2;
    const float2* Kr1 = Kr0 + (size_t)4*NPIX;
    float2 v[2][5];
    #pragma unroll
    for (int q = 0; q < 5; ++q) { v[0][q] = Kr0[5*t+q]; v[1][q] = Kr1[5*t+q]; }
    #pragma unroll
    for (int q = 0; q < 5; ++q) { v[0][q] = shfl2(v[0][q], rt); v[1][q] = shfl2(v[1][q], rt); }
    fft320_inv_r<2>(v, tw5, Wf, sg);
    size_t cs0 = ((size_t)((b*NC + c0)*HW2) + row)*HW2;
    size_t cs1 = cs0 + (size_t)4*NPIX;
    #pragma unroll
    for (int j = 0; j < 5; ++j) {
      int n = t + 64*j;
      float2 cv0 = make_float2(csr[cs0+n], csi[cs0+n]);
      float2 cv1 = make_float2(csr[cs1+n], csi[cs1+n]);
      acc[j] = cadd(acc[j], cadd(cmulc(v[0][j], cv0), cmulc(v[1][j], cv1)));
    }
  }
  #pragma unroll
  for (int j = 0; j < 5; ++j) rows[w][t+64*j] = cscale(acc[j], sgn);
  __syncthreads();
  float m = mu[0];
  const float* pf = (const float*)(pv + ((size_t)(b*HW2) + row)*HW2);
  float*       qf = (float*)(qv + ((size_t)(b*HW2) + row)*HW2);
  const float* rf = (const float*)rows;
  for (int i = threadIdx.x; i < 640; i += 256) {
    float s = rf[i] + rf[640+i] + rf[1280+i] + rf[1920+i];
    qf[i] = s + m * pf[i];
  }
}

// ---------- reductions & CG scalar kernels (float4-vectorized) ----------
__global__ void k_dot_rr(const float4* __restrict__ r, float2* partials) {
  float s = 0.f;
  for (int i = blockIdx.x*blockDim.x + threadIdx.x; i < NVEC/2; i += gridDim.x*blockDim.x) {
    float4 v = r[i]; s += v.x*v.x + v.y*v.y + v.z*v.z + v.w*v.w;
  }
  __shared__ float buf[4];
  for (int off = 32; off; off >>= 1) s += __shfl_down(s, off, 64);
  int w = threadIdx.x >> 6, t = threadIdx.x & 63;
  if (t == 0) buf[w] = s;
  __syncthreads();
  if (threadIdx.x == 0) partials[blockIdx.x] = make_float2(buf[0]+buf[1]+buf[2]+buf[3], 0.f);
}
__global__ void k_rr_finish(const float2* __restrict__ partials, float2* scal) {
  float s = 0.f;
  for (int i = threadIdx.x; i < 256; i += blockDim.x) s += partials[i].x;
  __shared__ float buf[4];
  for (int off = 32; off; off >>= 1) s += __shfl_down(s, off, 64);
  int w = threadIdx.x >> 6, t = threadIdx.x & 63;
  if (t == 0) buf[w] = s;
  __syncthreads();
  if (threadIdx.x == 0) scal[0] = make_float2(buf[0]+buf[1]+buf[2]+buf[3], 0.f);
}
__global__ void k_dot_pq(const float4* __restrict__ q, const float4* __restrict__ p, float2* partials) {
  float sr = 0.f, si = 0.f;
  for (int i = blockIdx.x*blockDim.x + threadIdx.x; i < NVEC/2; i += gridDim.x*blockDim.x) {
    float4 qq = q[i], pp = p[i];
    sr += qq.x*pp.x + qq.y*pp.y + qq.z*pp.z + qq.w*pp.w;   // q*conj(p)
    si += qq.y*pp.x - qq.x*pp.y + qq.w*pp.z - qq.z*pp.w;
  }
  __shared__ float2 buf[4];
  for (int off = 32; off; off >>= 1) { sr += __shfl_down(sr, off, 64); si += __shfl_down(si, off, 64); }
  int w = threadIdx.x >> 6, t = threadIdx.x & 63;
  if (t == 0) buf[w] = make_float2(sr, si);
  __syncthreads();
  if (threadIdx.x == 0)
    partials[blockIdx.x] = make_float2(buf[0].x+buf[1].x+buf[2].x+buf[3].x,
                                       buf[0].y+buf[1].y+buf[2].y+buf[3].y);
}
__global__ void k_alpha(const float2* __restrict__ partials, float2* scal) {
  float sr = 0.f, si = 0.f;
  for (int i = threadIdx.x; i < 256; i += blockDim.x) { sr += partials[i].x; si += partials[i].y; }
  __shared__ float2 buf[4];
  for (int off = 32; off; off >>= 1) { sr += __shfl_down(sr, off, 64); si += __shfl_down(si, off, 64); }
  int w = threadIdx.x >> 6, t = threadIdx.x & 63;
  if (t == 0) buf[w] = make_float2(sr, si);
  __syncthreads();
  if (threadIdx.x == 0) {
    float pr = buf[0].x+buf[1].x+buf[2].x+buf[3].x;
    float pi = buf[0].y+buf[1].y+buf[2].y+buf[3].y;
    float rr = scal[0].x;
    float d = pr*pr + pi*pi;
    scal[1] = make_float2(rr*pr/d, -rr*pi/d);   // alpha = rr * conj(pq)/|pq|^2
  }
}
__global__ void k_update(float4* bv, float4* r, const float4* __restrict__ p,
                         const float4* __restrict__ q, const float2* __restrict__ scal,
                         float2* partials) {
  float2 al = scal[1];
  float s = 0.f;
  for (int i = blockIdx.x*blockDim.x + threadIdx.x; i < NVEC/2; i += gridDim.x*blockDim.x) {
    float4 pp = p[i], qq = q[i], bb = bv[i], rr = r[i];
    bb.x += al.x*pp.x - al.y*pp.y;  bb.y += al.x*pp.y + al.y*pp.x;
    bb.z += al.x*pp.z - al.y*pp.w;  bb.w += al.x*pp.w + al.y*pp.z;
    bv[i] = bb;
    rr.x -= al.x*qq.x - al.y*qq.y;  rr.y -= al.x*qq.y + al.y*qq.x;
    rr.z -= al.x*qq.z - al.y*qq.w;  rr.w -= al.x*qq.w + al.y*qq.z;
    r[i] = rr;
    s += rr.x*rr.x + rr.y*rr.y + rr.z*rr.z + rr.w*rr.w;
  }
  __shared__ float buf[4];
  for (int off = 32; off; off >>= 1) s += __shfl_down(s, off, 64);
  int w = threadIdx.x >> 6, t = threadIdx.x & 63;
  if (t == 0) buf[w] = s;
  __syncthreads();
  if (threadIdx.x == 0) partials[blockIdx.x] = make_float2(buf[0]+buf[1]+buf[2]+buf[3], 0.f);
}
__global__ void k_beta(const float2* __restrict__ partials, float2* scal) {
  float s = 0.f;
  for (int i = threadIdx.x; i < 256; i += blockDim.x) s += partials[i].x;
  __shared__ float buf[4];
  for (int off = 32; off; off >>= 1) s += __shfl_down(s, off, 64);
  int w = threadIdx.x >> 6, t = threadIdx.x & 63;
  if (t == 0) buf[w] = s;
  __syncthreads();
  if (threadIdx.x == 0) {
    float rrnew = buf[0]+buf[1]+buf[2]+buf[3];
    float rrold = scal[0].x;
    scal[2] = make_float2(rrnew/rrold, 0.f);
    scal[0] = make_float2(rrnew, 0.f);
  }
}
__global__ void k_pupdate(float4* p, const float4* __restrict__ r, const float2* __restrict__ scal) {
  float be = scal[2].x;
  for (int i = blockIdx.x*blockDim.x + threadIdx.x; i < NVEC/2; i += gridDim.x*blockDim.x) {
    float4 pp = p[i], rr = r[i];
    pp.x = rr.x + be*pp.x; pp.y = rr.y + be*pp.y;
    pp.z = rr.z + be*pp.z; pp.w = rr.w + be*pp.w;
    p[i] = pp;
  }
}
__global__ void k_output(const float2* __restrict__ bv, float* __restrict__ out) {
  int i = blockIdx.x*blockDim.x + threadIdx.x;
  if (i >= NVEC) return;
  int b = i / NPIX, hw = i % NPIX;
  float2 v = bv[i];
  out[(size_t)(b*2+0)*NPIX + hw] = v.x;
  out[(size_t)(b*2+1)*NPIX + hw] = v.y;
}

// ---------- host ----------
extern "C" void kernel_launch(void* const* d_in, const int* in_sizes, int n_in,
                              void* d_out, int out_size, void* d_ws, size_t ws_size,
                              hipStream_t stream) {
  const float* us  = (const float*)d_in[0];
  const float* rec = (const float*)d_in[1];
  const float* msk = (const float*)d_in[2];
  const float* csr = (const float*)d_in[3];
  const float* csi = (const float*)d_in[4];
  const float* mu  = (const float*)d_in[5];
  float* out = (float*)d_out;

  const size_t vecB = (size_t)NVEC * 8;
  int nb = NB;
  while (nb > 1 && ((size_t)nb*NC*NPIX*8 + 4*vecB + 320*8 + 256*8 + 64) > ws_size) nb >>= 1;

  char* w = (char*)d_ws; size_t off = 0;
  float2* K        = (float2*)(w + off); off += (size_t)nb*NC*NPIX*8;
  float2* rv       = (float2*)(w + off); off += vecB;
  float2* pv       = (float2*)(w + off); off += vecB;
  float2* bv       = (float2*)(w + off); off += vecB;
  float2* qv       = (float2*)(w + off); off += vecB;
  float2* twg      = (float2*)(w + off); off += 320*8;
  float2* partials = (float2*)(w + off); off += 256*8;
  float2* scal     = (float2*)(w + off);

  k_twiddle<<<dim3(2), dim3(256), 0, stream>>>(twg);
  k_init<<<dim3(NVEC/256), dim3(256), 0, stream>>>(us, rec, mu, rv, pv, bv);
  k_dot_rr<<<dim3(256), dim3(256), 0, stream>>>((const float4*)rv, partials);
  k_rr_finish<<<dim3(1), dim3(256), 0, stream>>>(partials, scal);

  for (int it = 0; it < CGI; ++it) {
    for (int b0 = 0; b0 < NB; b0 += nb) {
      k_proj_rowfft    <<<dim3(nb*NC*(HW2/2)/4), dim3(256), 0, stream>>>(pv, csr, csi, K, twg, b0);
      k_colfft_mask    <<<dim3(nb*NC*20),        dim3(512), 0, stream>>>(K, msk, twg, b0);
      k_irowfft_combine<<<dim3(nb*HW2),          dim3(256), 0, stream>>>(K, csr, csi, pv, qv, mu, twg, b0);
    }
    k_dot_pq <<<dim3(256), dim3(256), 0, stream>>>((const float4*)qv, (const float4*)pv, partials);
    k_alpha  <<<dim3(1),   dim3(256), 0, stream>>>(partials, scal);
    k_update <<<dim3(256), dim3(256), 0, stream>>>((float4*)bv, (float4*)rv, (const float4*)pv,
                                                   (const float4*)qv, scal, partials);
    k_beta   <<<dim3(1),   dim3(256), 0, stream>>>(partials, scal);
    k_pupdate<<<dim3(256), dim3(256), 0, stream>>>((float4*)pv, (const float4*)rv, scal);
  }
  k_output<<<dim3(NVEC/256), dim3(256), 0, stream>>>(bv, out);
}

// Round 10
// 1617.649 us; speedup vs baseline: 1.5129x; 1.1027x over previous
//
#include <hip/hip_runtime.h>

#define HW2 320
#define NB 8
#define NC 16
#define NPIX (HW2*HW2)        // 102400
#define NVEC (NB*NPIX)        // 819200
#define CGI 10
#define FSCALE (1.0f/102400.0f)  // ortho fwd (1/320) * ortho inv (1/320)

// ---------- complex helpers ----------
__device__ inline float2 cadd(float2 a, float2 b){return make_float2(a.x+b.x, a.y+b.y);}
__device__ inline float2 csub(float2 a, float2 b){return make_float2(a.x-b.x, a.y-b.y);}
__device__ inline float2 cmul(float2 a, float2 b){return make_float2(a.x*b.x-a.y*b.y, a.x*b.y+a.y*b.x);}
__device__ inline float2 cmulc(float2 a, float2 b){return make_float2(a.x*b.x+a.y*b.y, a.y*b.x-a.x*b.y);} // a*conj(b)
__device__ inline float2 cscale(float2 a, float s){return make_float2(a.x*s, a.y*s);}
__device__ inline int rev6(int t){ return (int)(__brev((unsigned)t) >> 26); }
__device__ inline float2 shflx2(float2 a, int m){ return make_float2(__shfl_xor(a.x,m,64), __shfl_xor(a.y,m,64)); }
__device__ inline float2 shfl2(float2 a, int l){ return make_float2(__shfl(a.x,l,64), __shfl(a.y,l,64)); }

// ---------- lane-xor exchange, cheapest instruction per distance ----------
// h=1,2: DPP quad_perm (VALU, no LDS). h=4,8,16: ds_swizzle BitMode imm
// (within-32 xor, no addr VGPR, no bank conflicts). h=32: ds_bpermute via shfl.
template<int H>
__device__ inline float2 xsh2t(float2 a) {
  if constexpr (H == 1) {
    return make_float2(
      __int_as_float(__builtin_amdgcn_mov_dpp(__float_as_int(a.x), 0xB1, 0xF, 0xF, true)),
      __int_as_float(__builtin_amdgcn_mov_dpp(__float_as_int(a.y), 0xB1, 0xF, 0xF, true)));
  } else if constexpr (H == 2) {
    return make_float2(
      __int_as_float(__builtin_amdgcn_mov_dpp(__float_as_int(a.x), 0x4E, 0xF, 0xF, true)),
      __int_as_float(__builtin_amdgcn_mov_dpp(__float_as_int(a.y), 0x4E, 0xF, 0xF, true)));
  } else if constexpr (H == 32) {
    return shflx2(a, 32);
  } else {
    constexpr int imm = (H << 10) | 0x1F;   // xor_mask=H, or=0, and=31
    return make_float2(
      __int_as_float(__builtin_amdgcn_ds_swizzle(__float_as_int(a.x), imm)),
      __int_as_float(__builtin_amdgcn_ds_swizzle(__float_as_int(a.y), imm)));
  }
}

// ---------- radix-5 (in registers). DIR=-1 fwd, +1 inv. Unnormalized. ----------
template<int DIR>
__device__ inline void radix5(float2 (&v)[5]) {
  const float c1 = 0.30901699437494745f, s1 = 0.9510565162951535f;
  const float c2 = -0.8090169943749473f, s2 = 0.5877852522924731f;
  float2 t1 = cadd(v[1], v[4]), t2 = csub(v[1], v[4]);
  float2 t3 = cadd(v[2], v[3]), t4 = csub(v[2], v[3]);
  float2 y0 = cadd(v[0], cadd(t1, t3));
  float2 a1 = make_float2(v[0].x + c1*t1.x + c2*t3.x, v[0].y + c1*t1.y + c2*t3.y);
  float2 a2 = make_float2(v[0].x + c2*t1.x + c1*t3.x, v[0].y + c2*t1.y + c1*t3.y);
  float2 b1 = make_float2(s1*t2.x + s2*t4.x, s1*t2.y + s2*t4.y);
  float2 b2 = make_float2(s2*t2.x - s1*t4.x, s2*t2.y - s1*t4.y);
  const float sg = (float)DIR;
  float2 ib1 = make_float2(-sg*b1.y, sg*b1.x);
  float2 ib2 = make_float2(-sg*b2.y, sg*b2.x);
  v[0] = y0;
  v[1] = cadd(a1, ib1); v[4] = csub(a1, ib1);
  v[2] = cadd(a2, ib2); v[3] = csub(a2, ib2);
}

// ---------- per-lane register twiddles, pre-selected for uniform butterflies ----------
// tw5[q-1] = w320^{q t};  Wf[s] for h=32>>s: (t&h) ? w320^{5*(t&(h-1))*(32/h)} : 1 ; sg[s]=+/-1
__device__ inline void load_tw(const float2* __restrict__ twg, int t,
                               float2 (&tw5)[4], float2 (&Wf)[6], float (&sg)[6]) {
  #pragma unroll
  for (int q = 1; q < 5; ++q) tw5[q-1] = twg[q*t];
  float2 tw[6];
  tw[0] = twg[5*(t&31)];
  tw[1] = twg[10*(t&15)];
  tw[2] = twg[20*(t&7)];
  tw[3] = twg[40*(t&3)];
  tw[4] = twg[80*(t&1)];
  tw[5] = make_float2(1.f, 0.f);
  #pragma unroll
  for (int s = 0; s < 6; ++s) {
    bool up = (t & (32 >> s)) != 0;
    Wf[s] = up ? tw[s] : make_float2(1.f, 0.f);
    sg[s] = up ? -1.f : 1.f;
  }
}

// ---------- butterfly stages (uniform FMA form) ----------
template<int H, int NCOL>
__device__ inline void bf_fwd(float2 (&v)[NCOL][5], float2 w, float st) {
  #pragma unroll
  for (int q = 0; q < 5; ++q)
    #pragma unroll
    for (int k = 0; k < NCOL; ++k) {
      float2 o = xsh2t<H>(v[k][q]);
      float2 tmp = make_float2(fmaf(st, v[k][q].x, o.x), fmaf(st, v[k][q].y, o.y));
      v[k][q] = cmul(tmp, w);
    }
}
template<int H, int NCOL>
__device__ inline void bf_inv(float2 (&v)[NCOL][5], float2 w, float st) {
  #pragma unroll
  for (int q = 0; q < 5; ++q)
    #pragma unroll
    for (int k = 0; k < NCOL; ++k) {
      float2 mine = cmulc(v[k][q], w);
      float2 o = xsh2t<H>(mine);
      v[k][q] = make_float2(fmaf(st, mine.x, o.x), fmaf(st, mine.y, o.y));
    }
}

// ---------- 320-pt FFT across one wave, NCOL interleaved columns ----------
// fwd: input  v[k][j] = x[t+64j]  ->  output v[k][q] = X[5*rev6(t)+q]
template<int NCOL>
__device__ inline void fft320_fwd_r(float2 (&v)[NCOL][5],
                                    const float2 (&tw5)[4], const float2 (&Wf)[6],
                                    const float (&sg)[6]) {
  #pragma unroll
  for (int k = 0; k < NCOL; ++k) radix5<-1>(v[k]);
  #pragma unroll
  for (int q = 1; q < 5; ++q)
    #pragma unroll
    for (int k = 0; k < NCOL; ++k) v[k][q] = cmul(v[k][q], tw5[q-1]);
  bf_fwd<32>(v, Wf[0], sg[0]);
  bf_fwd<16>(v, Wf[1], sg[1]);
  bf_fwd< 8>(v, Wf[2], sg[2]);
  bf_fwd< 4>(v, Wf[3], sg[3]);
  bf_fwd< 2>(v, Wf[4], sg[4]);
  bf_fwd< 1>(v, Wf[5], sg[5]);
}
// inv (unnormalized): input v[k][q] = Y[5*rev6(t)+q] -> output v[k][j] = z[t+64j]
template<int NCOL>
__device__ inline void fft320_inv_r(float2 (&v)[NCOL][5],
                                    const float2 (&tw5)[4], const float2 (&Wf)[6],
                                    const float (&sg)[6]) {
  bf_inv< 1>(v, Wf[5], sg[5]);
  bf_inv< 2>(v, Wf[4], sg[4]);
  bf_inv< 4>(v, Wf[3], sg[3]);
  bf_inv< 8>(v, Wf[2], sg[2]);
  bf_inv<16>(v, Wf[1], sg[1]);
  bf_inv<32>(v, Wf[0], sg[0]);
  #pragma unroll
  for (int q = 1; q < 5; ++q)
    #pragma unroll
    for (int k = 0; k < NCOL; ++k) v[k][q] = cmulc(v[k][q], tw5[q-1]);
  #pragma unroll
  for (int k = 0; k < NCOL; ++k) radix5<1>(v[k]);
}

// ---------- twiddle table init (double precision trig) ----------
__global__ void k_twiddle(float2* tw) {
  int m = blockIdx.x*blockDim.x + threadIdx.x;
  if (m < 320) {
    double a = -2.0 * 3.14159265358979323846 * (double)m / 320.0;
    tw[m] = make_float2((float)cos(a), (float)sin(a));
  }
}

// ---------- r = us + mu*rec ; p = r ; b = 0  (planar -> interleaved) ----------
__global__ void k_init(const float* __restrict__ us, const float* __restrict__ rec,
                       const float* __restrict__ mu,
                       float2* r, float2* p, float2* bv) {
  int i = blockIdx.x*blockDim.x + threadIdx.x;
  if (i >= NVEC) return;
  float m = mu[0];
  int b = i / NPIX, hw = i % NPIX;
  float re = us[(size_t)(b*2+0)*NPIX + hw] + m * rec[(size_t)(b*2+0)*NPIX + hw];
  float im = us[(size_t)(b*2+1)*NPIX + hw] + m * rec[(size_t)(b*2+1)*NPIX + hw];
  float2 v = make_float2(re, im);
  r[i] = v; p[i] = v; bv[i] = make_float2(0.f, 0.f);
}

// ---------- A: coil-project (p*csm*S) + forward row FFT -> K ----------
// 2 adjacent rows per wave (ILP=2). 4 waves/block -> 8 rows/block.
__global__ __launch_bounds__(256) void k_proj_rowfft(
    const float2* __restrict__ pv, const float* __restrict__ csr,
    const float* __restrict__ csi, float2* __restrict__ K,
    const float2* __restrict__ twg, int b0) {
  __shared__ float2 stage[8][320];
  int t = threadIdx.x & 63, w = threadIdx.x >> 6, rt = rev6(t);
  float2 tw5[4], Wf[6]; float sg[6];
  load_tw(twg, t, tw5, Wf, sg);
  int wid = blockIdx.x*4 + w;
  int rp  = wid % (HW2/2);           // row-pair index
  int c   = (wid / (HW2/2)) % NC;
  int bl  = wid / ((HW2/2)*NC);
  int b   = b0 + bl;
  int row0 = rp*2;
  const float2* prow = pv + ((size_t)(b*HW2) + row0)*HW2;
  size_t cs = ((size_t)((b*NC + c)*HW2) + row0)*HW2;
  float sgn0 = ((row0 + t) & 1) ? -1.f : 1.f;   // (-1)^{row+n}, n=t+64j
  float sgn1 = -sgn0;
  float2 v[2][5];
  #pragma unroll
  for (int j = 0; j < 5; ++j) {
    int n = t + 64*j;
    float2 cv0 = make_float2(csr[cs+n],     csi[cs+n]);
    float2 cv1 = make_float2(csr[cs+HW2+n], csi[cs+HW2+n]);
    v[0][j] = cscale(cmul(prow[n],     cv0), sgn0);
    v[1][j] = cscale(cmul(prow[HW2+n], cv1), sgn1);
  }
  fft320_fwd_r<2>(v, tw5, Wf, sg);
  #pragma unroll
  for (int q = 0; q < 5; ++q) {
    stage[w*2+0][5*rt + q] = v[0][q];   // wave-local reorder
    stage[w*2+1][5*rt + q] = v[1][q];
  }
  float2* Krow = K + ((size_t)((bl*NC + c)*HW2) + row0)*HW2;
  #pragma unroll
  for (int j = 0; j < 5; ++j) {
    Krow[t + 64*j]       = stage[w*2+0][t + 64*j];
    Krow[HW2 + t + 64*j] = stage[w*2+1][t + 64*j];
  }
}

// ---------- B: column FFT + mask*scale + column IFFT, in place on K ----------
// 512 threads = 8 waves; each wave owns 2 columns, interleaved (ILP=2).
// LDS: separate re/im b32 planes [320][17] (stride 17 dwords, gcd(17,32)=1 ->
// conflict-free) + u8 mask [320][20] (2-way). float4 global load/store phases.
__global__ __launch_bounds__(512, 4) void k_colfft_mask(
    float2* __restrict__ K, const float* __restrict__ mask,
    const float2* __restrict__ twg, int b0) {
  __shared__ float re[320][17];
  __shared__ float im[320][17];
  __shared__ unsigned char mk8[320][20];
  int tile = blockIdx.x % 20;
  int c    = (blockIdx.x/20) % NC;
  int bl   = blockIdx.x/(20*NC);
  int b    = b0 + bl;
  float2* Kimg = K + (size_t)(bl*NC + c)*NPIX;
  const float4* Kimg4 = (const float4*)Kimg;            // row stride 160 float4
  const float4* Mimg4 = (const float4*)(mask + (size_t)b*NPIX);  // row stride 80
  int t = threadIdx.x & 63, w = threadIdx.x >> 6, rt = rev6(t);
  float2 tw5[4], Wf[6]; float sg[6];
  load_tw(twg, t, tw5, Wf, sg);
  for (int idx = threadIdx.x; idx < 320*8; idx += 512) {
    int rw = idx >> 3, c4 = idx & 7;                    // 2 float2 per float4
    float4 v4 = Kimg4[(size_t)rw*160 + tile*8 + c4];
    re[rw][2*c4+0] = v4.x; im[rw][2*c4+0] = v4.y;
    re[rw][2*c4+1] = v4.z; im[rw][2*c4+1] = v4.w;
  }
  for (int idx = threadIdx.x; idx < 320*4; idx += 512) {
    int rw = idx >> 2, c4 = idx & 3;                    // 4 mask floats per float4
    float4 m4 = Mimg4[(size_t)rw*80 + tile*4 + c4];
    mk8[rw][4*c4+0] = (unsigned char)(m4.x != 0.f);
    mk8[rw][4*c4+1] = (unsigned char)(m4.y != 0.f);
    mk8[rw][4*c4+2] = (unsigned char)(m4.z != 0.f);
    mk8[rw][4*c4+3] = (unsigned char)(m4.w != 0.f);
  }
  __syncthreads();
  const int colA = w*2, colB = w*2 + 1;
  float2 v[2][5];
  #pragma unroll
  for (int j = 0; j < 5; ++j) {
    v[0][j] = make_float2(re[t+64*j][colA], im[t+64*j][colA]);
    v[1][j] = make_float2(re[t+64*j][colB], im[t+64*j][colB]);
  }
  fft320_fwd_r<2>(v, tw5, Wf, sg);
  #pragma unroll
  for (int q = 0; q < 5; ++q) {
    int rowk = 5*rt + q;
    float m0 = mk8[rowk][colA] ? FSCALE : 0.f;
    float m1 = mk8[rowk][colB] ? FSCALE : 0.f;
    v[0][q] = cscale(v[0][q], m0);
    v[1][q] = cscale(v[1][q], m1);
  }
  fft320_inv_r<2>(v, tw5, Wf, sg);
  #pragma unroll
  for (int j = 0; j < 5; ++j) {
    re[t+64*j][colA] = v[0][j].x; im[t+64*j][colA] = v[0][j].y;
    re[t+64*j][colB] = v[1][j].x; im[t+64*j][colB] = v[1][j].y;
  }
  __syncthreads();
  float4* Kimg4w = (float4*)Kimg;
  for (int idx = threadIdx.x; idx < 320*8; idx += 512) {
    int rw = idx >> 3, c4 = idx & 7;
    float4 v4;
    v4.x = re[rw][2*c4+0]; v4.y = im[rw][2*c4+0];
    v4.z = re[rw][2*c4+1]; v4.w = im[rw][2*c4+1];
    Kimg4w[(size_t)rw*160 + tile*8 + c4] = v4;
  }
}

// ---------- C: inverse row FFT + sum_c conj(csm)*S + mu*p -> q ----------
// 2 coils interleaved per wave iteration (ILP=2).
__global__ __launch_bounds__(256) void k_irowfft_combine(
    const float2* __restrict__ K, const float* __restrict__ csr,
    const float* __restrict__ csi, const float2* __restrict__ pv,
    float2* __restrict__ qv, const float* __restrict__ mu,
    const float2* __restrict__ twg, int b0) {
  __shared__ float2 rows[4][320];
  int t = threadIdx.x & 63, w = threadIdx.x >> 6, rt = rev6(t);
  float2 tw5[4], Wf[6]; float sg[6];
  load_tw(twg, t, tw5, Wf, sg);
  int row = blockIdx.x % HW2;
  int bl  = blockIdx.x / HW2;
  int b   = b0 + bl;
  float sgn = ((row + t) & 1) ? -1.f : 1.f;
  float2 acc[5];
  #pragma unroll
  for (int j = 0; j < 5; ++j) acc[j] = make_float2(0.f, 0.f);
  #pragma unroll
  for (int half = 0; half < 2; ++half) {
    int c0 = w + 8*half;               // coils c0 and c0+4
    const float2* Kr0 = K + ((size_t)((bl*NC + c0)*HW2) + row)*HW2;
    const float2* Kr1 = Kr0 + (size_t)4*NPIX;
    float2 v[2][5];
    #pragma unroll
    for (int q = 0; q < 5; ++q) { v[0][q] = Kr0[5*t+q]; v[1][q] = Kr1[5*t+q]; }
    #pragma unroll
    for (int q = 0; q < 5; ++q) { v[0][q] = shfl2(v[0][q], rt); v[1][q] = shfl2(v[1][q], rt); }
    fft320_inv_r<2>(v, tw5, Wf, sg);
    size_t cs0 = ((size_t)((b*NC + c0)*HW2) + row)*HW2;
    size_t cs1 = cs0 + (size_t)4*NPIX;
    #pragma unroll
    for (int j = 0; j < 5; ++j) {
      int n = t + 64*j;
      float2 cv0 = make_float2(csr[cs0+n], csi[cs0+n]);
      float2 cv1 = make_float2(csr[cs1+n], csi[cs1+n]);
      acc[j] = cadd(acc[j], cadd(cmulc(v[0][j], cv0), cmulc(v[1][j], cv1)));
    }
  }
  #pragma unroll
  for (int j = 0; j < 5; ++j) rows[w][t+64*j] = cscale(acc[j], sgn);
  __syncthreads();
  float m = mu[0];
  const float* pf = (const float*)(pv + ((size_t)(b*HW2) + row)*HW2);
  float*       qf = (float*)(qv + ((size_t)(b*HW2) + row)*HW2);
  const float* rf = (const float*)rows;
  for (int i = threadIdx.x; i < 640; i += 256) {
    float s = rf[i] + rf[640+i] + rf[1280+i] + rf[1920+i];
    qf[i] = s + m * pf[i];
  }
}

// ---------- reductions & CG scalar kernels (float4-vectorized) ----------
__global__ void k_dot_rr(const float4* __restrict__ r, float2* partials) {
  float s = 0.f;
  for (int i = blockIdx.x*blockDim.x + threadIdx.x; i < NVEC/2; i += gridDim.x*blockDim.x) {
    float4 v = r[i]; s += v.x*v.x + v.y*v.y + v.z*v.z + v.w*v.w;
  }
  __shared__ float buf[4];
  for (int off = 32; off; off >>= 1) s += __shfl_down(s, off, 64);
  int w = threadIdx.x >> 6, t = threadIdx.x & 63;
  if (t == 0) buf[w] = s;
  __syncthreads();
  if (threadIdx.x == 0) partials[blockIdx.x] = make_float2(buf[0]+buf[1]+buf[2]+buf[3], 0.f);
}
__global__ void k_rr_finish(const float2* __restrict__ partials, float2* scal) {
  float s = 0.f;
  for (int i = threadIdx.x; i < 256; i += blockDim.x) s += partials[i].x;
  __shared__ float buf[4];
  for (int off = 32; off; off >>= 1) s += __shfl_down(s, off, 64);
  int w = threadIdx.x >> 6, t = threadIdx.x & 63;
  if (t == 0) buf[w] = s;
  __syncthreads();
  if (threadIdx.x == 0) scal[0] = make_float2(buf[0]+buf[1]+buf[2]+buf[3], 0.f);
}
__global__ void k_dot_pq(const float4* __restrict__ q, const float4* __restrict__ p, float2* partials) {
  float sr = 0.f, si = 0.f;
  for (int i = blockIdx.x*blockDim.x + threadIdx.x; i < NVEC/2; i += gridDim.x*blockDim.x) {
    float4 qq = q[i], pp = p[i];
    sr += qq.x*pp.x + qq.y*pp.y + qq.z*pp.z + qq.w*pp.w;   // q*conj(p)
    si += qq.y*pp.x - qq.x*pp.y + qq.w*pp.z - qq.z*pp.w;
  }
  __shared__ float2 buf[4];
  for (int off = 32; off; off >>= 1) { sr += __shfl_down(sr, off, 64); si += __shfl_down(si, off, 64); }
  int w = threadIdx.x >> 6, t = threadIdx.x & 63;
  if (t == 0) buf[w] = make_float2(sr, si);
  __syncthreads();
  if (threadIdx.x == 0)
    partials[blockIdx.x] = make_float2(buf[0].x+buf[1].x+buf[2].x+buf[3].x,
                                       buf[0].y+buf[1].y+buf[2].y+buf[3].y);
}
__global__ void k_alpha(const float2* __restrict__ partials, float2* scal) {
  float sr = 0.f, si = 0.f;
  for (int i = threadIdx.x; i < 256; i += blockDim.x) { sr += partials[i].x; si += partials[i].y; }
  __shared__ float2 buf[4];
  for (int off = 32; off; off >>= 1) { sr += __shfl_down(sr, off, 64); si += __shfl_down(si, off, 64); }
  int w = threadIdx.x >> 6, t = threadIdx.x & 63;
  if (t == 0) buf[w] = make_float2(sr, si);
  __syncthreads();
  if (threadIdx.x == 0) {
    float pr = buf[0].x+buf[1].x+buf[2].x+buf[3].x;
    float pi = buf[0].y+buf[1].y+buf[2].y+buf[3].y;
    float rr = scal[0].x;
    float d = pr*pr + pi*pi;
    scal[1] = make_float2(rr*pr/d, -rr*pi/d);   // alpha = rr * conj(pq)/|pq|^2
  }
}
__global__ void k_update(float4* bv, float4* r, const float4* __restrict__ p,
                         const float4* __restrict__ q, const float2* __restrict__ scal,
                         float2* partials) {
  float2 al = scal[1];
  float s = 0.f;
  for (int i = blockIdx.x*blockDim.x + threadIdx.x; i < NVEC/2; i += gridDim.x*blockDim.x) {
    float4 pp = p[i], qq = q[i], bb = bv[i], rr = r[i];
    bb.x += al.x*pp.x - al.y*pp.y;  bb.y += al.x*pp.y + al.y*pp.x;
    bb.z += al.x*pp.z - al.y*pp.w;  bb.w += al.x*pp.w + al.y*pp.z;
    bv[i] = bb;
    rr.x -= al.x*qq.x - al.y*qq.y;  rr.y -= al.x*qq.y + al.y*qq.x;
    rr.z -= al.x*qq.z - al.y*qq.w;  rr.w -= al.x*qq.w + al.y*qq.z;
    r[i] = rr;
    s += rr.x*rr.x + rr.y*rr.y + rr.z*rr.z + rr.w*rr.w;
  }
  __shared__ float buf[4];
  for (int off = 32; off; off >>= 1) s += __shfl_down(s, off, 64);
  int w = threadIdx.x >> 6, t = threadIdx.x & 63;
  if (t == 0) buf[w] = s;
  __syncthreads();
  if (threadIdx.x == 0) partials[blockIdx.x] = make_float2(buf[0]+buf[1]+buf[2]+buf[3], 0.f);
}
__global__ void k_beta(const float2* __restrict__ partials, float2* scal) {
  float s = 0.f;
  for (int i = threadIdx.x; i < 256; i += blockDim.x) s += partials[i].x;
  __shared__ float buf[4];
  for (int off = 32; off; off >>= 1) s += __shfl_down(s, off, 64);
  int w = threadIdx.x >> 6, t = threadIdx.x & 63;
  if (t == 0) buf[w] = s;
  __syncthreads();
  if (threadIdx.x == 0) {
    float rrnew = buf[0]+buf[1]+buf[2]+buf[3];
    float rrold = scal[0].x;
    scal[2] = make_float2(rrnew/rrold, 0.f);
    scal[0] = make_float2(rrnew, 0.f);
  }
}
__global__ void k_pupdate(float4* p, const float4* __restrict__ r, const float2* __restrict__ scal) {
  float be = scal[2].x;
  for (int i = blockIdx.x*blockDim.x + threadIdx.x; i < NVEC/2; i += gridDim.x*blockDim.x) {
    float4 pp = p[i], rr = r[i];
    pp.x = rr.x + be*pp.x; pp.y = rr.y + be*pp.y;
    pp.z = rr.z + be*pp.z; pp.w = rr.w + be*pp.w;
    p[i] = pp;
  }
}
__global__ void k_output(const float2* __restrict__ bv, float* __restrict__ out) {
  int i = blockIdx.x*blockDim.x + threadIdx.x;
  if (i >= NVEC) return;
  int b = i / NPIX, hw = i % NPIX;
  float2 v = bv[i];
  out[(size_t)(b*2+0)*NPIX + hw] = v.x;
  out[(size_t)(b*2+1)*NPIX + hw] = v.y;
}

// ---------- host ----------
extern "C" void kernel_launch(void* const* d_in, const int* in_sizes, int n_in,
                              void* d_out, int out_size, void* d_ws, size_t ws_size,
                              hipStream_t stream) {
  const float* us  = (const float*)d_in[0];
  const float* rec = (const float*)d_in[1];
  const float* msk = (const float*)d_in[2];
  const float* csr = (const float*)d_in[3];
  const float* csi = (const float*)d_in[4];
  const float* mu  = (const float*)d_in[5];
  float* out = (float*)d_out;

  const size_t vecB = (size_t)NVEC * 8;
  int nb = NB;
  while (nb > 1 && ((size_t)nb*NC*NPIX*8 + 4*vecB + 320*8 + 256*8 + 64) > ws_size) nb >>= 1;

  char* w = (char*)d_ws; size_t off = 0;
  float2* K        = (float2*)(w + off); off += (size_t)nb*NC*NPIX*8;
  float2* rv       = (float2*)(w + off); off += vecB;
  float2* pv       = (float2*)(w + off); off += vecB;
  float2* bv       = (float2*)(w + off); off += vecB;
  float2* qv       = (float2*)(w + off); off += vecB;
  float2* twg      = (float2*)(w + off); off += 320*8;
  float2* partials = (float2*)(w + off); off += 256*8;
  float2* scal     = (float2*)(w + off);

  k_twiddle<<<dim3(2), dim3(256), 0, stream>>>(twg);
  k_init<<<dim3(NVEC/256), dim3(256), 0, stream>>>(us, rec, mu, rv, pv, bv);
  k_dot_rr<<<dim3(256), dim3(256), 0, stream>>>((const float4*)rv, partials);
  k_rr_finish<<<dim3(1), dim3(256), 0, stream>>>(partials, scal);

  for (int it = 0; it < CGI; ++it) {
    for (int b0 = 0; b0 < NB; b0 += nb) {
      k_proj_rowfft    <<<dim3(nb*NC*(HW2/2)/4), dim3(256), 0, stream>>>(pv, csr, csi, K, twg, b0);
      k_colfft_mask    <<<dim3(nb*NC*20),        dim3(512), 0, stream>>>(K, msk, twg, b0);
      k_irowfft_combine<<<dim3(nb*HW2),          dim3(256), 0, stream>>>(K, csr, csi, pv, qv, mu, twg, b0);
    }
    k_dot_pq <<<dim3(256), dim3(256), 0, stream>>>((const float4*)qv, (const float4*)pv, partials);
    k_alpha  <<<dim3(1),   dim3(256), 0, stream>>>(partials, scal);
    k_update <<<dim3(256), dim3(256), 0, stream>>>((float4*)bv, (float4*)rv, (const float4*)pv,
                                                   (const float4*)qv, scal, partials);
    k_beta   <<<dim3(1),   dim3(256), 0, stream>>>(partials, scal);
    k_pupdate<<<dim3(256), dim3(256), 0, stream>>>((float4*)pv, (const float4*)rv, scal);
  }
  k_output<<<dim3(NVEC/256), dim3(256), 0, stream>>>(bv, out);
}

// Round 11
// 1596.680 us; speedup vs baseline: 1.5327x; 1.0131x over previous
//
#include <hip/hip_runtime.h>

#define HW2 320
#define NB 8
#define NC 16
#define NPIX (HW2*HW2)        // 102400
#define NVEC (NB*NPIX)        // 819200
#define CGI 10
#define FSCALE (1.0f/102400.0f)  // ortho fwd (1/320) * ortho inv (1/320)

// ---------- complex helpers ----------
__device__ inline float2 cadd(float2 a, float2 b){return make_float2(a.x+b.x, a.y+b.y);}
__device__ inline float2 csub(float2 a, float2 b){return make_float2(a.x-b.x, a.y-b.y);}
__device__ inline float2 cmul(float2 a, float2 b){return make_float2(a.x*b.x-a.y*b.y, a.x*b.y+a.y*b.x);}
__device__ inline float2 cmulc(float2 a, float2 b){return make_float2(a.x*b.x+a.y*b.y, a.y*b.x-a.x*b.y);} // a*conj(b)
__device__ inline float2 cscale(float2 a, float s){return make_float2(a.x*s, a.y*s);}
__device__ inline int rev6(int t){ return (int)(__brev((unsigned)t) >> 26); }
__device__ inline float2 shflx2(float2 a, int m){ return make_float2(__shfl_xor(a.x,m,64), __shfl_xor(a.y,m,64)); }

// ---------- lane-xor exchange, cheapest instruction per distance ----------
// h=1,2: DPP quad_perm; h=8: DPP row_ror:8 ((i+8)%16 == i^8); h=4,16: ds_swizzle
// BitMode imm; h=32: ds_bpermute via shfl.
template<int H>
__device__ inline float2 xsh2t(float2 a) {
  if constexpr (H == 1) {
    return make_float2(
      __int_as_float(__builtin_amdgcn_mov_dpp(__float_as_int(a.x), 0xB1, 0xF, 0xF, true)),
      __int_as_float(__builtin_amdgcn_mov_dpp(__float_as_int(a.y), 0xB1, 0xF, 0xF, true)));
  } else if constexpr (H == 2) {
    return make_float2(
      __int_as_float(__builtin_amdgcn_mov_dpp(__float_as_int(a.x), 0x4E, 0xF, 0xF, true)),
      __int_as_float(__builtin_amdgcn_mov_dpp(__float_as_int(a.y), 0x4E, 0xF, 0xF, true)));
  } else if constexpr (H == 8) {
    return make_float2(
      __int_as_float(__builtin_amdgcn_mov_dpp(__float_as_int(a.x), 0x128, 0xF, 0xF, true)),
      __int_as_float(__builtin_amdgcn_mov_dpp(__float_as_int(a.y), 0x128, 0xF, 0xF, true)));
  } else if constexpr (H == 32) {
    return shflx2(a, 32);
  } else {
    constexpr int imm = (H << 10) | 0x1F;   // xor_mask=H, or=0, and=31
    return make_float2(
      __int_as_float(__builtin_amdgcn_ds_swizzle(__float_as_int(a.x), imm)),
      __int_as_float(__builtin_amdgcn_ds_swizzle(__float_as_int(a.y), imm)));
  }
}

// ---------- radix-5 (in registers). DIR=-1 fwd, +1 inv. Unnormalized. ----------
template<int DIR>
__device__ inline void radix5(float2 (&v)[5]) {
  const float c1 = 0.30901699437494745f, s1 = 0.9510565162951535f;
  const float c2 = -0.8090169943749473f, s2 = 0.5877852522924731f;
  float2 t1 = cadd(v[1], v[4]), t2 = csub(v[1], v[4]);
  float2 t3 = cadd(v[2], v[3]), t4 = csub(v[2], v[3]);
  float2 y0 = cadd(v[0], cadd(t1, t3));
  float2 a1 = make_float2(v[0].x + c1*t1.x + c2*t3.x, v[0].y + c1*t1.y + c2*t3.y);
  float2 a2 = make_float2(v[0].x + c2*t1.x + c1*t3.x, v[0].y + c2*t1.y + c1*t3.y);
  float2 b1 = make_float2(s1*t2.x + s2*t4.x, s1*t2.y + s2*t4.y);
  float2 b2 = make_float2(s2*t2.x - s1*t4.x, s2*t2.y - s1*t4.y);
  const float sg = (float)DIR;
  float2 ib1 = make_float2(-sg*b1.y, sg*b1.x);
  float2 ib2 = make_float2(-sg*b2.y, sg*b2.x);
  v[0] = y0;
  v[1] = cadd(a1, ib1); v[4] = csub(a1, ib1);
  v[2] = cadd(a2, ib2); v[3] = csub(a2, ib2);
}

// ---------- per-lane register twiddles, pre-selected for uniform butterflies ----------
__device__ inline void load_tw(const float2* __restrict__ twg, int t,
                               float2 (&tw5)[4], float2 (&Wf)[6], float (&sg)[6]) {
  #pragma unroll
  for (int q = 1; q < 5; ++q) tw5[q-1] = twg[q*t];
  float2 tw[6];
  tw[0] = twg[5*(t&31)];
  tw[1] = twg[10*(t&15)];
  tw[2] = twg[20*(t&7)];
  tw[3] = twg[40*(t&3)];
  tw[4] = twg[80*(t&1)];
  tw[5] = make_float2(1.f, 0.f);
  #pragma unroll
  for (int s = 0; s < 6; ++s) {
    bool up = (t & (32 >> s)) != 0;
    Wf[s] = up ? tw[s] : make_float2(1.f, 0.f);
    sg[s] = up ? -1.f : 1.f;
  }
}

// ---------- butterfly stages (uniform FMA form) ----------
template<int H, int NCOL>
__device__ inline void bf_fwd(float2 (&v)[NCOL][5], float2 w, float st) {
  #pragma unroll
  for (int q = 0; q < 5; ++q)
    #pragma unroll
    for (int k = 0; k < NCOL; ++k) {
      float2 o = xsh2t<H>(v[k][q]);
      float2 tmp = make_float2(fmaf(st, v[k][q].x, o.x), fmaf(st, v[k][q].y, o.y));
      v[k][q] = cmul(tmp, w);
    }
}
template<int H, int NCOL>
__device__ inline void bf_inv(float2 (&v)[NCOL][5], float2 w, float st) {
  #pragma unroll
  for (int q = 0; q < 5; ++q)
    #pragma unroll
    for (int k = 0; k < NCOL; ++k) {
      float2 mine = cmulc(v[k][q], w);
      float2 o = xsh2t<H>(mine);
      v[k][q] = make_float2(fmaf(st, mine.x, o.x), fmaf(st, mine.y, o.y));
    }
}

// ---------- 320-pt FFT across one wave, NCOL interleaved columns ----------
// fwd: input  v[k][j] = x[t+64j]  ->  output v[k][q] = X[5*rev6(t)+q]
template<int NCOL>
__device__ inline void fft320_fwd_r(float2 (&v)[NCOL][5],
                                    const float2 (&tw5)[4], const float2 (&Wf)[6],
                                    const float (&sg)[6]) {
  #pragma unroll
  for (int k = 0; k < NCOL; ++k) radix5<-1>(v[k]);
  #pragma unroll
  for (int q = 1; q < 5; ++q)
    #pragma unroll
    for (int k = 0; k < NCOL; ++k) v[k][q] = cmul(v[k][q], tw5[q-1]);
  bf_fwd<32>(v, Wf[0], sg[0]);
  bf_fwd<16>(v, Wf[1], sg[1]);
  bf_fwd< 8>(v, Wf[2], sg[2]);
  bf_fwd< 4>(v, Wf[3], sg[3]);
  bf_fwd< 2>(v, Wf[4], sg[4]);
  bf_fwd< 1>(v, Wf[5], sg[5]);
}
// inv (unnormalized): input v[k][q] = Y[5*rev6(t)+q] -> output v[k][j] = z[t+64j]
template<int NCOL>
__device__ inline void fft320_inv_r(float2 (&v)[NCOL][5],
                                    const float2 (&tw5)[4], const float2 (&Wf)[6],
                                    const float (&sg)[6]) {
  bf_inv< 1>(v, Wf[5], sg[5]);
  bf_inv< 2>(v, Wf[4], sg[4]);
  bf_inv< 4>(v, Wf[3], sg[3]);
  bf_inv< 8>(v, Wf[2], sg[2]);
  bf_inv<16>(v, Wf[1], sg[1]);
  bf_inv<32>(v, Wf[0], sg[0]);
  #pragma unroll
  for (int q = 1; q < 5; ++q)
    #pragma unroll
    for (int k = 0; k < NCOL; ++k) v[k][q] = cmulc(v[k][q], tw5[q-1]);
  #pragma unroll
  for (int k = 0; k < NCOL; ++k) radix5<1>(v[k]);
}

// ---------- twiddle table init (double precision trig) ----------
__global__ void k_twiddle(float2* tw) {
  int m = blockIdx.x*blockDim.x + threadIdx.x;
  if (m < 320) {
    double a = -2.0 * 3.14159265358979323846 * (double)m / 320.0;
    tw[m] = make_float2((float)cos(a), (float)sin(a));
  }
}

// ---------- permuted binary mask: mp[b][kh][p] = mask[b][kh][kw(p)] != 0 ----------
// stored position p holds W-frequency kw = 5*rev6(p&63) + (p>>6)
__global__ void k_maskperm(const float* __restrict__ mask, unsigned char* __restrict__ mp) {
  int i = blockIdx.x*blockDim.x + threadIdx.x;
  if (i >= NVEC) return;
  int p = i % HW2;
  int rowb = i / HW2;   // (b*320 + kh)
  int kw = 5*rev6(p & 63) + (p >> 6);
  mp[i] = (unsigned char)(mask[(size_t)rowb*HW2 + kw] != 0.f);
}

// ---------- r = us + mu*rec ; p = r ; b = 0  (planar -> interleaved) ----------
__global__ void k_init(const float* __restrict__ us, const float* __restrict__ rec,
                       const float* __restrict__ mu,
                       float2* r, float2* p, float2* bv) {
  int i = blockIdx.x*blockDim.x + threadIdx.x;
  if (i >= NVEC) return;
  float m = mu[0];
  int b = i / NPIX, hw = i % NPIX;
  float re = us[(size_t)(b*2+0)*NPIX + hw] + m * rec[(size_t)(b*2+0)*NPIX + hw];
  float im = us[(size_t)(b*2+1)*NPIX + hw] + m * rec[(size_t)(b*2+1)*NPIX + hw];
  float2 v = make_float2(re, im);
  r[i] = v; p[i] = v; bv[i] = make_float2(0.f, 0.f);
}

// ---------- A: coil-project (p*csm*S) + forward row FFT -> K (digit-planar) ----------
// K row stores X[5*rev6(t)+q] at position q*64+t -> store instr q is lane-coalesced.
// 2 adjacent rows per wave (ILP=2), no LDS.
__global__ __launch_bounds__(256) void k_proj_rowfft(
    const float2* __restrict__ pv, const float* __restrict__ csr,
    const float* __restrict__ csi, float2* __restrict__ K,
    const float2* __restrict__ twg, int b0) {
  int t = threadIdx.x & 63, w = threadIdx.x >> 6;
  float2 tw5[4], Wf[6]; float sg[6];
  load_tw(twg, t, tw5, Wf, sg);
  int wid = blockIdx.x*4 + w;
  int rp  = wid % (HW2/2);           // row-pair index
  int c   = (wid / (HW2/2)) % NC;
  int bl  = wid / ((HW2/2)*NC);
  int b   = b0 + bl;
  int row0 = rp*2;
  const float2* prow = pv + ((size_t)(b*HW2) + row0)*HW2;
  size_t cs = ((size_t)((b*NC + c)*HW2) + row0)*HW2;
  float sgn0 = ((row0 + t) & 1) ? -1.f : 1.f;   // (-1)^{row+n}, n=t+64j
  float sgn1 = -sgn0;
  float2 v[2][5];
  #pragma unroll
  for (int j = 0; j < 5; ++j) {
    int n = t + 64*j;
    float2 cv0 = make_float2(csr[cs+n],     csi[cs+n]);
    float2 cv1 = make_float2(csr[cs+HW2+n], csi[cs+HW2+n]);
    v[0][j] = cscale(cmul(prow[n],     cv0), sgn0);
    v[1][j] = cscale(cmul(prow[HW2+n], cv1), sgn1);
  }
  fft320_fwd_r<2>(v, tw5, Wf, sg);
  float2* Krow = K + ((size_t)((bl*NC + c)*HW2) + row0)*HW2;
  #pragma unroll
  for (int q = 0; q < 5; ++q) {
    Krow[64*q + t]       = v[0][q];
    Krow[HW2 + 64*q + t] = v[1][q];
  }
}

// ---------- B: column FFT + mask*scale + column IFFT, in place on K ----------
// 512 threads = 8 waves; each wave owns 2 stored-columns, interleaved (ILP=2).
// LDS: re/im b32 planes [320][17] (conflict-free) + u8 mask [320][20] (2-way).
// Mask comes from the precomputed permuted u8 buffer (coalesced uchar4 loads).
__global__ __launch_bounds__(512, 4) void k_colfft_mask(
    float2* __restrict__ K, const unsigned char* __restrict__ mp,
    const float2* __restrict__ twg, int b0) {
  __shared__ float re[320][17];
  __shared__ float im[320][17];
  __shared__ unsigned char mk8[320][20];
  int tile = blockIdx.x % 20;
  int c    = (blockIdx.x/20) % NC;
  int bl   = blockIdx.x/(20*NC);
  int b    = b0 + bl;
  float2* Kimg = K + (size_t)(bl*NC + c)*NPIX;
  const float4* Kimg4 = (const float4*)Kimg;                 // row stride 160 float4
  const uchar4* Mp4   = (const uchar4*)(mp + (size_t)b*NPIX); // row stride 80 uchar4
  int t = threadIdx.x & 63, w = threadIdx.x >> 6, rt = rev6(t);
  float2 tw5[4], Wf[6]; float sg[6];
  load_tw(twg, t, tw5, Wf, sg);
  for (int idx = threadIdx.x; idx < 320*8; idx += 512) {
    int rw = idx >> 3, c4 = idx & 7;                    // 2 float2 per float4
    float4 v4 = Kimg4[(size_t)rw*160 + tile*8 + c4];
    re[rw][2*c4+0] = v4.x; im[rw][2*c4+0] = v4.y;
    re[rw][2*c4+1] = v4.z; im[rw][2*c4+1] = v4.w;
  }
  for (int idx = threadIdx.x; idx < 320*4; idx += 512) {
    int rw = idx >> 2, c4 = idx & 3;                    // 4 u8 per uchar4
    uchar4 m4 = Mp4[(size_t)rw*80 + tile*4 + c4];
    mk8[rw][4*c4+0] = m4.x;
    mk8[rw][4*c4+1] = m4.y;
    mk8[rw][4*c4+2] = m4.z;
    mk8[rw][4*c4+3] = m4.w;
  }
  __syncthreads();
  const int colA = w*2, colB = w*2 + 1;
  float2 v[2][5];
  #pragma unroll
  for (int j = 0; j < 5; ++j) {
    v[0][j] = make_float2(re[t+64*j][colA], im[t+64*j][colA]);
    v[1][j] = make_float2(re[t+64*j][colB], im[t+64*j][colB]);
  }
  fft320_fwd_r<2>(v, tw5, Wf, sg);
  #pragma unroll
  for (int q = 0; q < 5; ++q) {
    int rowk = 5*rt + q;
    float m0 = mk8[rowk][colA] ? FSCALE : 0.f;
    float m1 = mk8[rowk][colB] ? FSCALE : 0.f;
    v[0][q] = cscale(v[0][q], m0);
    v[1][q] = cscale(v[1][q], m1);
  }
  fft320_inv_r<2>(v, tw5, Wf, sg);
  #pragma unroll
  for (int j = 0; j < 5; ++j) {
    re[t+64*j][colA] = v[0][j].x; im[t+64*j][colA] = v[0][j].y;
    re[t+64*j][colB] = v[1][j].x; im[t+64*j][colB] = v[1][j].y;
  }
  __syncthreads();
  float4* Kimg4w = (float4*)Kimg;
  for (int idx = threadIdx.x; idx < 320*8; idx += 512) {
    int rw = idx >> 3, c4 = idx & 7;
    float4 v4;
    v4.x = re[rw][2*c4+0]; v4.y = im[rw][2*c4+0];
    v4.z = re[rw][2*c4+1]; v4.w = im[rw][2*c4+1];
    Kimg4w[(size_t)rw*160 + tile*8 + c4] = v4;
  }
}

// ---------- C: inverse row FFT + sum_c conj(csm)*S + mu*p -> q ----------
// Digit-planar K: lane t reg q reads K[64q+t] (coalesced) which is already the
// fft320_inv input order -> no shfl. 2 coils interleaved per wave (ILP=2).
__global__ __launch_bounds__(256) void k_irowfft_combine(
    const float2* __restrict__ K, const float* __restrict__ csr,
    const float* __restrict__ csi, const float2* __restrict__ pv,
    float2* __restrict__ qv, const float* __restrict__ mu,
    const float2* __restrict__ twg, int b0) {
  __shared__ float2 rows[4][320];
  int t = threadIdx.x & 63, w = threadIdx.x >> 6;
  float2 tw5[4], Wf[6]; float sg[6];
  load_tw(twg, t, tw5, Wf, sg);
  int row = blockIdx.x % HW2;
  int bl  = blockIdx.x / HW2;
  int b   = b0 + bl;
  float sgn = ((row + t) & 1) ? -1.f : 1.f;
  float2 acc[5];
  #pragma unroll
  for (int j = 0; j < 5; ++j) acc[j] = make_float2(0.f, 0.f);
  #pragma unroll
  for (int half = 0; half < 2; ++half) {
    int c0 = w + 8*half;               // coils c0 and c0+4
    const float2* Kr0 = K + ((size_t)((bl*NC + c0)*HW2) + row)*HW2;
    const float2* Kr1 = Kr0 + (size_t)4*NPIX;
    float2 v[2][5];
    #pragma unroll
    for (int q = 0; q < 5; ++q) { v[0][q] = Kr0[64*q + t]; v[1][q] = Kr1[64*q + t]; }
    fft320_inv_r<2>(v, tw5, Wf, sg);
    size_t cs0 = ((size_t)((b*NC + c0)*HW2) + row)*HW2;
    size_t cs1 = cs0 + (size_t)4*NPIX;
    #pragma unroll
    for (int j = 0; j < 5; ++j) {
      int n = t + 64*j;
      float2 cv0 = make_float2(csr[cs0+n], csi[cs0+n]);
      float2 cv1 = make_float2(csr[cs1+n], csi[cs1+n]);
      acc[j] = cadd(acc[j], cadd(cmulc(v[0][j], cv0), cmulc(v[1][j], cv1)));
    }
  }
  #pragma unroll
  for (int j = 0; j < 5; ++j) rows[w][t+64*j] = cscale(acc[j], sgn);
  __syncthreads();
  float m = mu[0];
  const float* pf = (const float*)(pv + ((size_t)(b*HW2) + row)*HW2);
  float*       qf = (float*)(qv + ((size_t)(b*HW2) + row)*HW2);
  const float* rf = (const float*)rows;
  for (int i = threadIdx.x; i < 640; i += 256) {
    float s = rf[i] + rf[640+i] + rf[1280+i] + rf[1920+i];
    qf[i] = s + m * pf[i];
  }
}

// ---------- reductions & CG scalar kernels ----------
__global__ void k_dot_rr(const float4* __restrict__ r, float2* partials) {
  float s = 0.f;
  for (int i = blockIdx.x*blockDim.x + threadIdx.x; i < NVEC/2; i += gridDim.x*blockDim.x) {
    float4 v = r[i]; s += v.x*v.x + v.y*v.y + v.z*v.z + v.w*v.w;
  }
  __shared__ float buf[4];
  for (int off = 32; off; off >>= 1) s += __shfl_down(s, off, 64);
  int w = threadIdx.x >> 6, t = threadIdx.x & 63;
  if (t == 0) buf[w] = s;
  __syncthreads();
  if (threadIdx.x == 0) partials[blockIdx.x] = make_float2(buf[0]+buf[1]+buf[2]+buf[3], 0.f);
}
__global__ void k_rr_finish(const float2* __restrict__ partials, float* rrslot) {
  float s = 0.f;
  for (int i = threadIdx.x; i < 256; i += blockDim.x) s += partials[i].x;
  __shared__ float buf[4];
  for (int off = 32; off; off >>= 1) s += __shfl_down(s, off, 64);
  int w = threadIdx.x >> 6, t = threadIdx.x & 63;
  if (t == 0) buf[w] = s;
  __syncthreads();
  if (threadIdx.x == 0) rrslot[0] = buf[0]+buf[1]+buf[2]+buf[3];
}
__global__ void k_dot_pq(const float4* __restrict__ q, const float4* __restrict__ p, float2* partials) {
  float sr = 0.f, si = 0.f;
  for (int i = blockIdx.x*blockDim.x + threadIdx.x; i < NVEC/2; i += gridDim.x*blockDim.x) {
    float4 qq = q[i], pp = p[i];
    sr += qq.x*pp.x + qq.y*pp.y + qq.z*pp.z + qq.w*pp.w;   // q*conj(p)
    si += qq.y*pp.x - qq.x*pp.y + qq.w*pp.z - qq.z*pp.w;
  }
  __shared__ float2 buf[4];
  for (int off = 32; off; off >>= 1) { sr += __shfl_down(sr, off, 64); si += __shfl_down(si, off, 64); }
  int w = threadIdx.x >> 6, t = threadIdx.x & 63;
  if (t == 0) buf[w] = make_float2(sr, si);
  __syncthreads();
  if (threadIdx.x == 0)
    partials[blockIdx.x] = make_float2(buf[0].x+buf[1].x+buf[2].x+buf[3].x,
                                       buf[0].y+buf[1].y+buf[2].y+buf[3].y);
}
// alpha folded in: each block reduces partials_pq identically (deterministic),
// then does b += alpha*p ; r -= alpha*q ; writes rr_new partials.
__global__ void k_update(float4* bv, float4* r, const float4* __restrict__ p,
                         const float4* __restrict__ q,
                         const float2* __restrict__ partials_pq,
                         const float* __restrict__ rrslot, int it,
                         float2* partials_rr) {
  __shared__ float2 abuf[4];
  {
    float2 pq = partials_pq[threadIdx.x];   // 256 threads <-> 256 partials
    float sr = pq.x, si = pq.y;
    for (int off = 32; off; off >>= 1) { sr += __shfl_down(sr, off, 64); si += __shfl_down(si, off, 64); }
    int w0 = threadIdx.x >> 6, t0 = threadIdx.x & 63;
    if (t0 == 0) abuf[w0] = make_float2(sr, si);
  }
  __syncthreads();
  float pr = abuf[0].x+abuf[1].x+abuf[2].x+abuf[3].x;
  float pi = abuf[0].y+abuf[1].y+abuf[2].y+abuf[3].y;
  float rr = rrslot[it];
  float d = pr*pr + pi*pi;
  float2 al = make_float2(rr*pr/d, -rr*pi/d);
  float s = 0.f;
  for (int i = blockIdx.x*blockDim.x + threadIdx.x; i < NVEC/2; i += gridDim.x*blockDim.x) {
    float4 pp = p[i], qq = q[i], bb = bv[i], rv = r[i];
    bb.x += al.x*pp.x - al.y*pp.y;  bb.y += al.x*pp.y + al.y*pp.x;
    bb.z += al.x*pp.z - al.y*pp.w;  bb.w += al.x*pp.w + al.y*pp.z;
    bv[i] = bb;
    rv.x -= al.x*qq.x - al.y*qq.y;  rv.y -= al.x*qq.y + al.y*qq.x;
    rv.z -= al.x*qq.z - al.y*qq.w;  rv.w -= al.x*qq.w + al.y*qq.z;
    r[i] = rv;
    s += rv.x*rv.x + rv.y*rv.y + rv.z*rv.z + rv.w*rv.w;
  }
  __shared__ float buf[4];
  for (int off = 32; off; off >>= 1) s += __shfl_down(s, off, 64);
  int w = threadIdx.x >> 6, t = threadIdx.x & 63;
  if (t == 0) buf[w] = s;
  __syncthreads();
  if (threadIdx.x == 0) partials_rr[blockIdx.x] = make_float2(buf[0]+buf[1]+buf[2]+buf[3], 0.f);
}
// beta folded in: each block reduces partials_rr identically; block 0 stores
// rr_new into rrslot[it+1] (consumed only by the NEXT kernel in stream order).
__global__ void k_pupdate(float4* p, const float4* __restrict__ r,
                          const float2* __restrict__ partials_rr,
                          float* rrslot, int it) {
  __shared__ float bbuf[4];
  {
    float s0 = partials_rr[threadIdx.x].x;
    for (int off = 32; off; off >>= 1) s0 += __shfl_down(s0, off, 64);
    int w0 = threadIdx.x >> 6, t0 = threadIdx.x & 63;
    if (t0 == 0) bbuf[w0] = s0;
  }
  __syncthreads();
  float rrnew = bbuf[0]+bbuf[1]+bbuf[2]+bbuf[3];
  float be = rrnew / rrslot[it];
  for (int i = blockIdx.x*blockDim.x + threadIdx.x; i < NVEC/2; i += gridDim.x*blockDim.x) {
    float4 pp = p[i], rv = r[i];
    pp.x = rv.x + be*pp.x; pp.y = rv.y + be*pp.y;
    pp.z = rv.z + be*pp.z; pp.w = rv.w + be*pp.w;
    p[i] = pp;
  }
  if (blockIdx.x == 0 && threadIdx.x == 0) rrslot[it+1] = rrnew;
}
__global__ void k_output(const float2* __restrict__ bv, float* __restrict__ out) {
  int i = blockIdx.x*blockDim.x + threadIdx.x;
  if (i >= NVEC) return;
  int b = i / NPIX, hw = i % NPIX;
  float2 v = bv[i];
  out[(size_t)(b*2+0)*NPIX + hw] = v.x;
  out[(size_t)(b*2+1)*NPIX + hw] = v.y;
}

// ---------- host ----------
extern "C" void kernel_launch(void* const* d_in, const int* in_sizes, int n_in,
                              void* d_out, int out_size, void* d_ws, size_t ws_size,
                              hipStream_t stream) {
  const float* us  = (const float*)d_in[0];
  const float* rec = (const float*)d_in[1];
  const float* msk = (const float*)d_in[2];
  const float* csr = (const float*)d_in[3];
  const float* csi = (const float*)d_in[4];
  const float* mu  = (const float*)d_in[5];
  float* out = (float*)d_out;

  const size_t vecB = (size_t)NVEC * 8;
  int nb = NB;
  while (nb > 1 &&
         ((size_t)nb*NC*NPIX*8 + 4*vecB + 320*8 + 2*256*8 + 64 + NVEC + 64) > ws_size)
    nb >>= 1;

  char* w = (char*)d_ws; size_t off = 0;
  float2* K           = (float2*)(w + off); off += (size_t)nb*NC*NPIX*8;
  float2* rv          = (float2*)(w + off); off += vecB;
  float2* pv          = (float2*)(w + off); off += vecB;
  float2* bv          = (float2*)(w + off); off += vecB;
  float2* qv          = (float2*)(w + off); off += vecB;
  float2* twg         = (float2*)(w + off); off += 320*8;
  float2* partials_pq = (float2*)(w + off); off += 256*8;
  float2* partials_rr = (float2*)(w + off); off += 256*8;
  float*  rrslot      = (float*)(w + off);  off += 64;
  unsigned char* mp   = (unsigned char*)(w + off); off += NVEC;

  k_twiddle <<<dim3(2),        dim3(256), 0, stream>>>(twg);
  k_maskperm<<<dim3(NVEC/256), dim3(256), 0, stream>>>(msk, mp);
  k_init    <<<dim3(NVEC/256), dim3(256), 0, stream>>>(us, rec, mu, rv, pv, bv);
  k_dot_rr  <<<dim3(256),      dim3(256), 0, stream>>>((const float4*)rv, partials_rr);
  k_rr_finish<<<dim3(1),       dim3(256), 0, stream>>>(partials_rr, rrslot);

  for (int it = 0; it < CGI; ++it) {
    for (int b0 = 0; b0 < NB; b0 += nb) {
      k_proj_rowfft    <<<dim3(nb*NC*(HW2/2)/4), dim3(256), 0, stream>>>(pv, csr, csi, K, twg, b0);
      k_colfft_mask    <<<dim3(nb*NC*20),        dim3(512), 0, stream>>>(K, mp, twg, b0);
      k_irowfft_combine<<<dim3(nb*HW2),          dim3(256), 0, stream>>>(K, csr, csi, pv, qv, mu, twg, b0);
    }
    k_dot_pq <<<dim3(256), dim3(256), 0, stream>>>((const float4*)qv, (const float4*)pv, partials_pq);
    k_update <<<dim3(256), dim3(256), 0, stream>>>((float4*)bv, (float4*)rv, (const float4*)pv,
                                                   (const float4*)qv, partials_pq, rrslot, it,
                                                   partials_rr);
    k_pupdate<<<dim3(256), dim3(256), 0, stream>>>((float4*)pv, (const float4*)rv, partials_rr,
                                                   rrslot, it);
  }
  k_output<<<dim3(NVEC/256), dim3(256), 0, stream>>>(bv, out);
}